// Round 13
// baseline (3475.286 us; speedup 1.0000x reference)
//
#include <hip/hip_runtime.h>
#include <hip/hip_bf16.h>

// HGT forward, MI355X. Round 18 (resubmit; prior bench was an infra failure).
// Dispatch consolidation (27 -> 13) + revert pool fusion per R17 decision
// rule (pool_lin 103us >= 85 threshold).
// R17 post-mortem: fusion was a wash (103 ~= 66+25+traffic). New theory:
// sum(per-dispatch) ~505us vs wall 719us -> ~210us of launch gaps + tail
// drains across ~27 serial dispatches. Fix: (1) one qkv_all dispatch/layer
// (stmt-A NM3 + stmt-B NM2 + func NM3 grids concatenated; tails overlap);
// (2) CSR 9->3 dispatches (contiguous deg/rowstart; per-relation pos arrays,
// +1.6MB ws < proven 214.5MB); (3) emb2bf+transp_w+make_wr_all -> prep_all.
// pool_embed (R16, 66us proven) + prologue gemm_2t_reg restored.
// Decision rule: wall drop <30us -> launch-gap theory wrong, instrument next.

typedef __hip_bfloat16 bf16;
typedef __attribute__((ext_vector_type(8))) short short8;
typedef __attribute__((ext_vector_type(4))) short s4v;
typedef __attribute__((ext_vector_type(4))) float floatx4;

#define N_STMT 100000
#define N_FUNC 50000
#define N_TOT  150000
#define EDGES  200000
#define CCH 128
#define RPB2 96    // rows/block, 2t kernels (6 iters of 16)
#define GS2 1042   // ceil(100000/96)
#define GF2 521    // ceil(50000/96)
#define GA 782     // ceil(100000/128) stmt A blocks (NM=3, rpb=128)
#define GB 1042    // ceil(100000/96)  stmt B blocks (NM=2, rpb=96)
#define GF 391     // ceil(50000/128)  func blocks   (NM=3, rpb=128)
#define EB 782     // ceil(EDGES/256)

__device__ __forceinline__ float b2f(bf16 x){ return __bfloat162float(x); }
__device__ __forceinline__ float bs2f(short s){
  union { short s; bf16 h; } u; u.s = s; return __bfloat162float(u.h);
}
__device__ __forceinline__ short f2bs(float x){
  union { bf16 h; short s; } u; u.h = __float2bfloat16(x); return u.s;
}
__device__ __forceinline__ float blo(unsigned u){ return __uint_as_float(u << 16); }
__device__ __forceinline__ float bhi(unsigned u){ return __uint_as_float(u & 0xffff0000u); }
// tanh-form gelu via single exp: 0.5x(1+tanh(u)) = x - x/(e^{2u}+1)
__device__ __forceinline__ float gelu_f(float x){
  float z = 1.5957691216057308f * (x + 0.044715f * x * x * x);
  float t = __expf(z);
  return x - x / (t + 1.f);
}

// -------- combined one-time prep: emb2bf + transp_w + make_wr_all -----------
// flat grid: [0,3125) emb2bf | [3125,3765) transp_w | [3765,4533) make_wr_all
__global__ __launch_bounds__(256) void prep_all(
    const float* __restrict__ emb, bf16* __restrict__ ebf,
    const float* __restrict__ lin_w, const float* __restrict__ qw,
    const float* __restrict__ aw, bf16* __restrict__ WT,
    const float* __restrict__ kw, const float* __restrict__ kb,
    const float* __restrict__ vw, const float* __restrict__ vb,
    const float* __restrict__ a_rel, const float* __restrict__ m_rel,
    bf16* __restrict__ WRT, float* __restrict__ Bf)
{
  int bid = blockIdx.x;
  if (bid < 3125) {
    long i = ((long)bid * 256 + threadIdx.x) * 8;
    float4 f0 = *(const float4*)(emb + i);
    float4 f1 = *(const float4*)(emb + i + 4);
    short8 o;
    o[0]=f2bs(f0.x); o[1]=f2bs(f0.y); o[2]=f2bs(f0.z); o[3]=f2bs(f0.w);
    o[4]=f2bs(f1.x); o[5]=f2bs(f1.y); o[6]=f2bs(f1.z); o[7]=f2bs(f1.w);
    *(short8*)(ebf + i) = o;
  } else if (bid < 3765) {
    int lb = bid - 3125;
    int mat = lb >> 6;
    const float* src = (mat < 2) ? lin_w + mat * 16384
                     : (mat < 6) ? qw + (mat - 2) * 16384
                                 : aw + (mat - 6) * 16384;
    bf16* dst = WT + mat * 16384;
    int idx = (lb & 63) * 256 + threadIdx.x;     // n*128+k
    int n = idx >> 7, k = idx & 127;
    dst[idx] = __float2bfloat16(src[k * 128 + n]);
  } else {
    int lb = bid - 3765;
    int y = lb >> 6;
    bool isV = y >= 6;
    int z = isV ? y - 6 : y;
    int l = z / 3, r = z % 3, st = (r == 2) ? 1 : 0;
    const float* W   = (isV ? vw : kw) + (l * 2 + st) * 16384;
    const float* b   = (isV ? vb : kb) + (l * 2 + st) * 128;
    const float* rel = (isV ? m_rel : a_rel) + z * 2048;
    bf16* Wrt = WRT + y * 16384;
    float* br = Bf + y * 128;

    int idx = (lb & 63) * 256 + threadIdx.x;
    if (idx < 128 * 128) {
      int c = idx >> 7, o = idx & 127;
      int h = o >> 4, e = o & 15;
      float acc = 0.f;
#pragma unroll
      for (int d = 0; d < 16; d++)
        acc += W[c * 128 + h * 16 + d] * rel[h * 256 + d * 16 + e];
      Wrt[o * 128 + c] = __float2bfloat16(acc);
    }
    if (idx < 128) {
      int h = idx >> 4, e = idx & 15;
      float acc = 0.f;
#pragma unroll
      for (int d = 0; d < 16; d++)
        acc += b[h * 16 + d] * rel[h * 256 + d * 16 + e];
      br[idx] = acc;
    }
  }
}

// ---------------- pooled embedding: one wave per node -----------------------
__global__ __launch_bounds__(256) void pool_embed(
    const int* __restrict__ tok_s, const int* __restrict__ tok_f,
    const bf16* __restrict__ ebf, bf16* __restrict__ E_out)
{
  int n = blockIdx.x * 4 + (threadIdx.x >> 6);
  int lane = threadIdx.x & 63, g = lane >> 4, c16 = lane & 15;
  const int* tok = (n < N_STMT) ? (tok_s + n * 16) : (tok_f + (n - N_STMT) * 16);
  float acc[8] = {0.f,0.f,0.f,0.f,0.f,0.f,0.f,0.f};
#pragma unroll
  for (int j = 0; j < 4; j++) {
    int v = tok[g * 4 + j];
    short8 row = *(const short8*)(ebf + (long)v * CCH + c16 * 8);
#pragma unroll
    for (int q = 0; q < 8; q++) acc[q] += bs2f(row[q]);
  }
#pragma unroll
  for (int q = 0; q < 8; q++) {
    acc[q] += __shfl_xor(acc[q], 16);
    acc[q] += __shfl_xor(acc[q], 32);
  }
  if (g == 0) {
    short8 o;
#pragma unroll
    for (int q = 0; q < 8; q++) o[q] = f2bs(fmaxf(acc[q] * (1.f/16.f), 0.f));
    *(short8*)(E_out + (long)n * CCH + c16 * 8) = o;
  }
}

// -------- 2-type GEMM, register-resident weights, pipelined A ---------------
template <bool RELU, bool BLEND, bool OUT_BF16>
__global__ __launch_bounds__(256) void gemm_2t_reg(
    const bf16* __restrict__ Ab, const bf16* __restrict__ Wt0,
    const bf16* __restrict__ Wt1, const float* __restrict__ bias0,
    const float* __restrict__ bias1, const bf16* __restrict__ oldx,
    void* __restrict__ dstv, const float* __restrict__ skip2)
{
  const int wave = threadIdx.x >> 6, lane = threadIdx.x & 63;
  const int lane15 = lane & 15, quad = lane >> 4;
  const int jc0 = wave * 2;
  const int bid = blockIdx.x;
  const int type = (bid >= GS2);
  const long base = type ? (long)N_STMT * CCH : 0;
  const int Nrows = type ? N_FUNC : N_STMT;
  long row = (long)(type ? bid - GS2 : bid) * RPB2;
  long rowEnd = row + RPB2; if (rowEnd > Nrows) rowEnd = Nrows;
  const bf16* Wt = type ? Wt1 : Wt0;
  const float* bias = type ? bias1 : bias0;

  short8 w[2][4];
#pragma unroll
  for (int jj = 0; jj < 2; jj++)
#pragma unroll
    for (int kq = 0; kq < 4; kq++)
      w[jj][kq] = *(const short8*)(
          Wt + ((jc0 + jj) * 16 + lane15) * CCH + kq * 32 + quad * 8);
  float4 bb[2];
#pragma unroll
  for (int jj = 0; jj < 2; jj++)
    bb[jj] = *(const float4*)(bias + (jc0 + jj) * 16 + quad * 4);

  float g = 1.f, gi = 0.f;
  if (BLEND) {
    float sk = skip2[type];
    g = 1.f / (1.f + expf(-sk));
    gi = 1.f - g;
  }

  // prime first A tile
  short8 a[4];
  {
    long r = row + lane15; if (r >= Nrows) r = Nrows - 1;
#pragma unroll
    for (int kq = 0; kq < 4; kq++)
      a[kq] = *(const short8*)(Ab + base + r * CCH + kq * 32 + quad * 8);
  }

  for (; row < rowEnd; row += 16) {
    short8 an[4];
    {
      long nrow = (row + 16 < rowEnd) ? row + 16 : row;
      long r = nrow + lane15; if (r >= Nrows) r = Nrows - 1;
#pragma unroll
      for (int kq = 0; kq < 4; kq++)
        an[kq] = *(const short8*)(Ab + base + r * CCH + kq * 32 + quad * 8);
    }

    floatx4 acc[2];
#pragma unroll
    for (int jj = 0; jj < 2; jj++) {
      acc[jj][0] = bb[jj].x; acc[jj][1] = bb[jj].y;
      acc[jj][2] = bb[jj].z; acc[jj][3] = bb[jj].w;
    }
#pragma unroll
    for (int kq = 0; kq < 4; kq++)
#pragma unroll
      for (int jj = 0; jj < 2; jj++)
        acc[jj] = __builtin_amdgcn_mfma_f32_16x16x32_bf16(
            w[jj][kq], a[kq], acc[jj], 0, 0, 0);

    long r = row + lane15;
    if (r < Nrows) {
#pragma unroll
      for (int jj = 0; jj < 2; jj++) {
        int c0 = (jc0 + jj) * 16 + quad * 4;
        long idx = base + r * CCH + c0;
        float v[4];
#pragma unroll
        for (int q = 0; q < 4; q++) v[q] = acc[jj][q];
        if (RELU) {
#pragma unroll
          for (int q = 0; q < 4; q++) v[q] = fmaxf(v[q], 0.f);
        }
        if (BLEND) {
          s4v ov = *(const s4v*)(oldx + idx);
#pragma unroll
          for (int q = 0; q < 4; q++) v[q] = g * v[q] + gi * bs2f(ov[q]);
        }
        if (OUT_BF16) {
          s4v o;
#pragma unroll
          for (int q = 0; q < 4; q++) o[q] = f2bs(v[q]);
          *(s4v*)((bf16*)dstv + idx) = o;
        } else {
          float4 o = make_float4(v[0], v[1], v[2], v[3]);
          *(float4*)((float*)dstv + idx) = o;
        }
      }
    }
#pragma unroll
    for (int kq = 0; kq < 4; kq++) a[kq] = an[kq];
  }
}

// ------------ QKV body, register-resident weights, jc-split waves -----------
template <int NM, bool HASQ>
__device__ __forceinline__ void qkv_body(
    const bf16* __restrict__ Ab,
    const bf16* __restrict__ W0, const float* __restrict__ B0,
    const bf16* __restrict__ W1, const float* __restrict__ B1,
    const bf16* __restrict__ W2, const float* __restrict__ B2,
    bf16* __restrict__ Q, bf16* __restrict__ KV, int N, int rpb, int bid)
{
  const int wave = threadIdx.x >> 6, lane = threadIdx.x & 63;
  const int lane15 = lane & 15, quad = lane >> 4;
  const int jc0 = wave * 2;
  constexpr int KIDX = HASQ ? 1 : 0;
  constexpr int VIDX = KIDX + 1;

  long row = (long)bid * rpb;
  if (row >= N) return;
  long rowEnd = row + rpb; if (rowEnd > N) rowEnd = N;

  const bf16* Wm[3]  = {W0, W1, W2};
  const float* Bm[3] = {B0, B1, B2};

  short8 w[NM][2][4];
#pragma unroll
  for (int m = 0; m < NM; m++)
#pragma unroll
    for (int jj = 0; jj < 2; jj++)
#pragma unroll
      for (int kq = 0; kq < 4; kq++)
        w[m][jj][kq] = *(const short8*)(
            Wm[m] + ((jc0 + jj) * 16 + lane15) * CCH + kq * 32 + quad * 8);

  for (; row < rowEnd; row += 16) {
    long r = row + lane15;
    long rc = (r < N) ? r : (N - 1);
    short8 a[4];
#pragma unroll
    for (int kq = 0; kq < 4; kq++)
      a[kq] = *(const short8*)(Ab + rc * CCH + kq * 32 + quad * 8);

    floatx4 acc[NM][2];
#pragma unroll
    for (int m = 0; m < NM; m++)
#pragma unroll
      for (int jj = 0; jj < 2; jj++) {
        float4 bb = *(const float4*)(Bm[m] + (jc0 + jj) * 16 + quad * 4);
        acc[m][jj][0] = bb.x; acc[m][jj][1] = bb.y;
        acc[m][jj][2] = bb.z; acc[m][jj][3] = bb.w;
      }

#pragma unroll
    for (int kq = 0; kq < 4; kq++)
#pragma unroll
      for (int m = 0; m < NM; m++)
#pragma unroll
        for (int jj = 0; jj < 2; jj++)
          acc[m][jj] = __builtin_amdgcn_mfma_f32_16x16x32_bf16(
              w[m][jj][kq], a[kq], acc[m][jj], 0, 0, 0);

    if (r < N) {
#pragma unroll
      for (int jj = 0; jj < 2; jj++) {
        int c0 = (jc0 + jj) * 16 + quad * 4;
        if constexpr (HASQ) {
          s4v qo;
          qo[0] = f2bs(acc[0][jj][0]);
          qo[1] = f2bs(acc[0][jj][1]);
          qo[2] = f2bs(acc[0][jj][2]);
          qo[3] = f2bs(acc[0][jj][3]);
          *(s4v*)(Q + r * CCH + c0) = qo;
        }
        short8 kv;
        kv[0] = f2bs(acc[KIDX][jj][0]);
        kv[1] = f2bs(acc[KIDX][jj][1]);
        kv[2] = f2bs(acc[VIDX][jj][0]);
        kv[3] = f2bs(acc[VIDX][jj][1]);
        kv[4] = f2bs(acc[KIDX][jj][2]);
        kv[5] = f2bs(acc[KIDX][jj][3]);
        kv[6] = f2bs(acc[VIDX][jj][2]);
        kv[7] = f2bs(acc[VIDX][jj][3]);
        *(short8*)(KV + r * 256 + 2 * c0) = kv;
      }
    }
  }
}

// ------ all three QKV GEMMs of one layer in a single dispatch ---------------
__global__ __launch_bounds__(256, 3) void qkv_all(
    const bf16* __restrict__ Xb, const bf16* __restrict__ WT,
    const bf16* __restrict__ WRT, const float* __restrict__ Bf,
    const float* __restrict__ qb,
    bf16* __restrict__ Qb, bf16* __restrict__ KV0,
    bf16* __restrict__ KV1, bf16* __restrict__ KV2, int l)
{
  const int bid = blockIdx.x;
  const int z0 = l * 3 + 0, z1 = l * 3 + 1, z2 = l * 3 + 2;
  if (bid < GA) {
    qkv_body<3, true>(Xb,
        WT + (2 + l * 2) * 16384, qb + (l * 2) * 128,
        WRT + z0 * 16384, Bf + z0 * 128,
        WRT + (6 + z0) * 16384, Bf + (6 + z0) * 128,
        Qb, KV0, N_STMT, 128, bid);
  } else if (bid < GA + GB) {
    qkv_body<2, false>(Xb,
        WRT + z1 * 16384, Bf + z1 * 128,
        WRT + (6 + z1) * 16384, Bf + (6 + z1) * 128,
        nullptr, nullptr,
        nullptr, KV1, N_STMT, 96, bid - GA);
  } else {
    qkv_body<3, true>(Xb + (long)N_STMT * CCH,
        WT + (2 + l * 2 + 1) * 16384, qb + (l * 2 + 1) * 128,
        WRT + z2 * 16384, Bf + z2 * 128,
        WRT + (6 + z2) * 16384, Bf + (6 + z2) * 128,
        Qb + (long)N_STMT * CCH, KV2, N_FUNC, 128, bid - GA - GB);
  }
}

// ---------------- CSR build, all 3 relations per dispatch -------------------
__global__ __launch_bounds__(256) void csr_count_all(
    const int* __restrict__ d0, const int* __restrict__ d1,
    const int* __restrict__ d2, int* __restrict__ degf,
    int* __restrict__ posf)
{
  int r = blockIdx.x / EB;
  int e = (blockIdx.x % EB) * 256 + threadIdx.x;
  if (e < EDGES) {
    const int* dst = r == 0 ? d0 : r == 1 ? d1 : d2;
    int off = r == 0 ? 0 : r == 1 ? 100000 : 150000;
    posf[r * EDGES + e] = atomicAdd(&degf[off + dst[e]], 1);
  }
}
__global__ __launch_bounds__(256) void csr_alloc_all(
    const int* __restrict__ degf, int* __restrict__ rowstartf,
    int* __restrict__ total)
{
  int n = blockIdx.x * 256 + threadIdx.x;
  if (n < 250000) {
    int r = (n < 100000) ? 0 : (n < 150000) ? 1 : 2;
    rowstartf[n] = atomicAdd(total + r, degf[n]);
  }
}
__global__ __launch_bounds__(256) void csr_fill_all(
    const int* __restrict__ d0, const int* __restrict__ d1,
    const int* __restrict__ d2, const int* __restrict__ s0,
    const int* __restrict__ s1, const int* __restrict__ s2,
    const int* __restrict__ rowstartf, const int* __restrict__ posf,
    int* __restrict__ srcs0, int* __restrict__ srcs1, int* __restrict__ srcs2)
{
  int r = blockIdx.x / EB;
  int e = (blockIdx.x % EB) * 256 + threadIdx.x;
  if (e < EDGES) {
    const int* dst = r == 0 ? d0 : r == 1 ? d1 : d2;
    const int* src = r == 0 ? s0 : r == 1 ? s1 : s2;
    int* sr = r == 0 ? srcs0 : r == 1 ? srcs1 : srcs2;
    int off = r == 0 ? 0 : r == 1 ? 100000 : 150000;
    sr[rowstartf[off + dst[e]] + posf[r * EDGES + e]] = src[e];
  }
}

// -------- per-relation message: 16-lane group, serial edges, no merges ------
__device__ __forceinline__ void relmsg_grp(
    int rs, int g, const int* __restrict__ srcs,
    const bf16* __restrict__ KV, float psc,
    const float* __restrict__ q, int lane, float* __restrict__ out)
{
  int p = lane & 15;
  int gbase = lane & 48;                 // first lane of this 16-lane group
  float den = 0.f;
  float a[8] = {0.f,0.f,0.f,0.f,0.f,0.f,0.f,0.f};
  for (int j0 = 0; j0 < g; j0 += 16) {
    int rem = g - j0; if (rem > 16) rem = 16;
    int sl = srcs[rs + j0 + (p < rem ? p : rem - 1)];
    for (int j = 0; j < rem; j++) {
      int s = __shfl(sl, gbase + j);
      const bf16* rowp = KV + (long)s * 256 + 16 * p;
      uint4 u0 = *(const uint4*)(rowp);
      uint4 u1 = *(const uint4*)(rowp + 8);
      float prod = q[0]*blo(u0.x) + q[1]*bhi(u0.x)
                 + q[2]*blo(u0.z) + q[3]*bhi(u0.z)
                 + q[4]*blo(u1.x) + q[5]*bhi(u1.x)
                 + q[6]*blo(u1.z) + q[7]*bhi(u1.z);
      prod += __shfl_xor(prod, 1);
      float ev = __expf(prod * psc);
      den += ev;
      a[0] += ev * blo(u0.y); a[1] += ev * bhi(u0.y);
      a[2] += ev * blo(u0.w); a[3] += ev * bhi(u0.w);
      a[4] += ev * blo(u1.y); a[5] += ev * bhi(u1.y);
      a[6] += ev * blo(u1.w); a[7] += ev * bhi(u1.w);
    }
  }
  float inv = 1.f / (den + 1e-16f);
#pragma unroll
  for (int i = 0; i < 8; i++) out[i] = a[i] * inv;
}

// -------- fused aggregation + GELU: 16 nodes per block (4 per wave) ---------
__global__ __launch_bounds__(256) void agg_all(
    const int* __restrict__ rs0, const int* __restrict__ dg0, const int* __restrict__ srcs0,
    const int* __restrict__ rs1, const int* __restrict__ dg1, const int* __restrict__ srcs1,
    const int* __restrict__ rs2, const int* __restrict__ dg2, const int* __restrict__ srcs2,
    const bf16* __restrict__ KV0, const bf16* __restrict__ KV1,
    const bf16* __restrict__ KV2, const float* __restrict__ pl,
    const bf16* __restrict__ Qb, bf16* __restrict__ AGGb)
{
  int n = blockIdx.x * 16 + (threadIdx.x >> 4);
  if (n >= N_TOT) return;
  int lane = threadIdx.x & 63;
  int p = lane & 15, h = p >> 1;
  uint4 qv = *(const uint4*)(Qb + (long)n * CCH + 8 * p);
  float q[8];
  q[0] = blo(qv.x); q[1] = bhi(qv.x); q[2] = blo(qv.y); q[3] = bhi(qv.y);
  q[4] = blo(qv.z); q[5] = bhi(qv.z); q[6] = blo(qv.w); q[7] = bhi(qv.w);
  float m[8];
  if (n < N_STMT) {
    float m0[8], m2[8];
    relmsg_grp(rs0[n], dg0[n], srcs0, KV0, pl[h] * 0.25f, q, lane, m0);
    relmsg_grp(rs2[n], dg2[n], srcs2, KV2, pl[16 + h] * 0.25f, q, lane, m2);
#pragma unroll
    for (int i = 0; i < 8; i++) m[i] = m0[i] + m2[i];
  } else {
    int nf = n - N_STMT;
    relmsg_grp(rs1[nf], dg1[nf], srcs1, KV1, pl[8 + h] * 0.25f, q, lane, m);
  }
  short8 o;
#pragma unroll
  for (int i = 0; i < 8; i++) o[i] = f2bs(gelu_f(m[i]));
  *(short8*)(AGGb + (long)n * CCH + 8 * p) = o;
}

__global__ __launch_bounds__(256) void zero_out_k(float* __restrict__ out)
{
  long i = ((long)blockIdx.x * 256 + threadIdx.x) * 4;
  *(float4*)(out + i) = make_float4(0.f, 0.f, 0.f, 0.f);
}

extern "C" void kernel_launch(void* const* d_in, const int* in_sizes, int n_in,
                              void* d_out, int out_size, void* d_ws, size_t ws_size,
                              hipStream_t stream)
{
  const int* tok_s = (const int*)d_in[0];
  const int* tok_f = (const int*)d_in[1];
  const int* esrc[3] = {(const int*)d_in[2], (const int*)d_in[4], (const int*)d_in[6]};
  const int* edst[3] = {(const int*)d_in[3], (const int*)d_in[5], (const int*)d_in[7]};
  const float* emb   = (const float*)d_in[8];
  const float* lin_w = (const float*)d_in[9];
  const float* lin_b = (const float*)d_in[10];
  const float* kw = (const float*)d_in[11];
  const float* kb = (const float*)d_in[12];
  const float* qw = (const float*)d_in[13];
  const float* qb = (const float*)d_in[14];
  const float* vw = (const float*)d_in[15];
  const float* vb = (const float*)d_in[16];
  const float* aw = (const float*)d_in[17];
  const float* ab = (const float*)d_in[18];
  const float* skip  = (const float*)d_in[19];
  const float* a_rel = (const float*)d_in[20];
  const float* m_rel = (const float*)d_in[21];
  const float* p_rel = (const float*)d_in[22];

  // ---- ws layout. ----
  float* Bf   = (float*)d_ws;           // 12 x 128 fused biases
  bf16*  Xb   = (bf16*)(Bf + 1536);     // 19,200,000  residual stream
  bf16*  AGGb = Xb  + 19200000L;        // 19,200,000  agg out (alias pooled E)
  bf16*  KV0  = AGGb + 19200000L;       // 25,600,000  stmt r0 KV interleaved
  bf16*  KV1  = KV0 + 25600000L;        // 25,600,000  stmt r1 KV
  bf16*  KV2  = KV1 + 25600000L;        // 12,800,000  func r2 KV
  bf16*  WT   = KV2 + 12800000L;        //    163,840  10 transposed raw mats
  bf16*  WRT  = WT  + 163840L;          //    196,608  12 fused rel mats
  int*   ip   = (int*)(WRT + 196608L);
  int* degf        = ip;                               // 250,000 contiguous
  int* total       = ip + 250000;                      // 4 counters (3 used)
  int* rowstartf   = ip + 250004;                      // 250,000 contiguous
  int* rowstart[3] = {ip + 250004, ip + 350004, ip + 400004};
  int* deg[3]      = {ip, ip + 100000, ip + 150000};
  int* srcs[3]     = {ip + 500004, ip + 700004, ip + 900004};
  int* posf        = ip + 1100004;                     // 3 x 200,000
  bf16* EBF   = KV0;                    // 6,400,000 alias: bf16 emb table,
                                        // dead before KV0 is first written
  bf16*  Qb   = (bf16*)d_out;          // bf16 Q scratch in fp32 d_out,
  float* OUTF = (float*)d_out;         // consumed before epilogue overwrites

  const size_t NEED = (size_t)1536 * 4 + (size_t)102760448 * 2
                    + (size_t)1700004 * 4;
  if (ws_size < NEED) {            // soft-fail diagnostic: absmax == |ref|max
    zero_out_k<<<19200000 / 4 / 256, 256, 0, stream>>>(OUTF);
    return;
  }

  // ---- CSR build: 3 dispatches for all relations ----
  hipMemsetAsync(ip, 0, (size_t)250004 * 4, stream);
  csr_count_all<<<3 * EB, 256, 0, stream>>>(
      edst[0], edst[1], edst[2], degf, posf);
  csr_alloc_all<<<(250000 + 255) / 256, 256, 0, stream>>>(
      degf, rowstartf, total);
  csr_fill_all<<<3 * EB, 256, 0, stream>>>(
      edst[0], edst[1], edst[2], esrc[0], esrc[1], esrc[2],
      rowstartf, posf, srcs[0], srcs[1], srcs[2]);

  // ---- one-time prep (emb2bf + transp_w + make_wr_all) ----
  prep_all<<<4533, 256, 0, stream>>>(
      emb, EBF, lin_w, qw, aw, WT, kw, kb, vw, vb, a_rel, m_rel, WRT, Bf);

  // ---- prologue: pooled embeddings -> fused per-type linear+relu -> Xb ----
  pool_embed<<<N_TOT / 4, 256, 0, stream>>>(tok_s, tok_f, EBF, AGGb);
  gemm_2t_reg<true, false, true><<<GS2 + GF2, 256, 0, stream>>>(
      AGGb, WT, WT + 16384, lin_b, lin_b + 128, nullptr, Xb, nullptr);

  for (int l = 0; l < 2; l++) {
    // all three QKV GEMMs in one dispatch
    qkv_all<<<GA + GB + GF, 256, 0, stream>>>(
        Xb, WT, WRT, Bf, qb, Qb, KV0, KV1, KV2, l);
    // fused aggregation (+GELU) over all nodes, 16 nodes/block
    agg_all<<<(N_TOT + 15) / 16, 256, 0, stream>>>(
        rowstart[0], deg[0], srcs[0], rowstart[1], deg[1], srcs[1],
        rowstart[2], deg[2], srcs[2], KV0, KV1, KV2,
        p_rel + l * 24, Qb, AGGb);
    // fused out-proj + gated skip blend. l=0 -> Xb; l=1 -> fp32 d_out.
    if (l == 0)
      gemm_2t_reg<false, true, true><<<GS2 + GF2, 256, 0, stream>>>(
          AGGb, WT + 6 * 16384, WT + 7 * 16384, ab, ab + 128,
          Xb, Xb, skip);
    else
      gemm_2t_reg<false, true, false><<<GS2 + GF2, 256, 0, stream>>>(
          AGGb, WT + 8 * 16384, WT + 9 * 16384, ab + 256, ab + 384,
          Xb, OUTF, skip + 2);
  }
}

// Round 14
// 679.207 us; speedup vs baseline: 5.1167x; 5.1167x over previous
//
#include <hip/hip_runtime.h>
#include <hip/hip_bf16.h>

// HGT forward, MI355X. Round 19: fix csr_alloc atomic-address uniformity.
// R18 post-mortem: consolidation WORKED (rest-of-net = 3475-2836 = 639us vs
// 719 before) but csr_alloc_all hit 2836us: computing r from thread's n made
// `total + r` non-wave-uniform -> LLVM's atomic optimizer (DPP wave-scan +
// 1 atomic/wave) could not fire -> 250k serialized same-line atomics.
// Fix: segment grid by relation (blocks [0,391) r=0, [391,587) r=1,
// [587,978) r=2) so r comes from blockIdx (SGPR) -> address wave-uniform ->
// ~4k wave atomics total. Everything else identical to R18.

typedef __hip_bfloat16 bf16;
typedef __attribute__((ext_vector_type(8))) short short8;
typedef __attribute__((ext_vector_type(4))) short s4v;
typedef __attribute__((ext_vector_type(4))) float floatx4;

#define N_STMT 100000
#define N_FUNC 50000
#define N_TOT  150000
#define EDGES  200000
#define CCH 128
#define RPB2 96    // rows/block, 2t kernels (6 iters of 16)
#define GS2 1042   // ceil(100000/96)
#define GF2 521    // ceil(50000/96)
#define GA 782     // ceil(100000/128) stmt A blocks (NM=3, rpb=128)
#define GB 1042    // ceil(100000/96)  stmt B blocks (NM=2, rpb=96)
#define GF 391     // ceil(50000/128)  func blocks   (NM=3, rpb=128)
#define EB 782     // ceil(EDGES/256)

__device__ __forceinline__ float b2f(bf16 x){ return __bfloat162float(x); }
__device__ __forceinline__ float bs2f(short s){
  union { short s; bf16 h; } u; u.s = s; return __bfloat162float(u.h);
}
__device__ __forceinline__ short f2bs(float x){
  union { bf16 h; short s; } u; u.h = __float2bfloat16(x); return u.s;
}
__device__ __forceinline__ float blo(unsigned u){ return __uint_as_float(u << 16); }
__device__ __forceinline__ float bhi(unsigned u){ return __uint_as_float(u & 0xffff0000u); }
// tanh-form gelu via single exp: 0.5x(1+tanh(u)) = x - x/(e^{2u}+1)
__device__ __forceinline__ float gelu_f(float x){
  float z = 1.5957691216057308f * (x + 0.044715f * x * x * x);
  float t = __expf(z);
  return x - x / (t + 1.f);
}

// -------- combined one-time prep: emb2bf + transp_w + make_wr_all -----------
// flat grid: [0,3125) emb2bf | [3125,3765) transp_w | [3765,4533) make_wr_all
__global__ __launch_bounds__(256) void prep_all(
    const float* __restrict__ emb, bf16* __restrict__ ebf,
    const float* __restrict__ lin_w, const float* __restrict__ qw,
    const float* __restrict__ aw, bf16* __restrict__ WT,
    const float* __restrict__ kw, const float* __restrict__ kb,
    const float* __restrict__ vw, const float* __restrict__ vb,
    const float* __restrict__ a_rel, const float* __restrict__ m_rel,
    bf16* __restrict__ WRT, float* __restrict__ Bf)
{
  int bid = blockIdx.x;
  if (bid < 3125) {
    long i = ((long)bid * 256 + threadIdx.x) * 8;
    float4 f0 = *(const float4*)(emb + i);
    float4 f1 = *(const float4*)(emb + i + 4);
    short8 o;
    o[0]=f2bs(f0.x); o[1]=f2bs(f0.y); o[2]=f2bs(f0.z); o[3]=f2bs(f0.w);
    o[4]=f2bs(f1.x); o[5]=f2bs(f1.y); o[6]=f2bs(f1.z); o[7]=f2bs(f1.w);
    *(short8*)(ebf + i) = o;
  } else if (bid < 3765) {
    int lb = bid - 3125;
    int mat = lb >> 6;
    const float* src = (mat < 2) ? lin_w + mat * 16384
                     : (mat < 6) ? qw + (mat - 2) * 16384
                                 : aw + (mat - 6) * 16384;
    bf16* dst = WT + mat * 16384;
    int idx = (lb & 63) * 256 + threadIdx.x;     // n*128+k
    int n = idx >> 7, k = idx & 127;
    dst[idx] = __float2bfloat16(src[k * 128 + n]);
  } else {
    int lb = bid - 3765;
    int y = lb >> 6;
    bool isV = y >= 6;
    int z = isV ? y - 6 : y;
    int l = z / 3, r = z % 3, st = (r == 2) ? 1 : 0;
    const float* W   = (isV ? vw : kw) + (l * 2 + st) * 16384;
    const float* b   = (isV ? vb : kb) + (l * 2 + st) * 128;
    const float* rel = (isV ? m_rel : a_rel) + z * 2048;
    bf16* Wrt = WRT + y * 16384;
    float* br = Bf + y * 128;

    int idx = (lb & 63) * 256 + threadIdx.x;
    if (idx < 128 * 128) {
      int c = idx >> 7, o = idx & 127;
      int h = o >> 4, e = o & 15;
      float acc = 0.f;
#pragma unroll
      for (int d = 0; d < 16; d++)
        acc += W[c * 128 + h * 16 + d] * rel[h * 256 + d * 16 + e];
      Wrt[o * 128 + c] = __float2bfloat16(acc);
    }
    if (idx < 128) {
      int h = idx >> 4, e = idx & 15;
      float acc = 0.f;
#pragma unroll
      for (int d = 0; d < 16; d++)
        acc += b[h * 16 + d] * rel[h * 256 + d * 16 + e];
      br[idx] = acc;
    }
  }
}

// ---------------- pooled embedding: one wave per node -----------------------
__global__ __launch_bounds__(256) void pool_embed(
    const int* __restrict__ tok_s, const int* __restrict__ tok_f,
    const bf16* __restrict__ ebf, bf16* __restrict__ E_out)
{
  int n = blockIdx.x * 4 + (threadIdx.x >> 6);
  int lane = threadIdx.x & 63, g = lane >> 4, c16 = lane & 15;
  const int* tok = (n < N_STMT) ? (tok_s + n * 16) : (tok_f + (n - N_STMT) * 16);
  float acc[8] = {0.f,0.f,0.f,0.f,0.f,0.f,0.f,0.f};
#pragma unroll
  for (int j = 0; j < 4; j++) {
    int v = tok[g * 4 + j];
    short8 row = *(const short8*)(ebf + (long)v * CCH + c16 * 8);
#pragma unroll
    for (int q = 0; q < 8; q++) acc[q] += bs2f(row[q]);
  }
#pragma unroll
  for (int q = 0; q < 8; q++) {
    acc[q] += __shfl_xor(acc[q], 16);
    acc[q] += __shfl_xor(acc[q], 32);
  }
  if (g == 0) {
    short8 o;
#pragma unroll
    for (int q = 0; q < 8; q++) o[q] = f2bs(fmaxf(acc[q] * (1.f/16.f), 0.f));
    *(short8*)(E_out + (long)n * CCH + c16 * 8) = o;
  }
}

// -------- 2-type GEMM, register-resident weights, pipelined A ---------------
template <bool RELU, bool BLEND, bool OUT_BF16>
__global__ __launch_bounds__(256) void gemm_2t_reg(
    const bf16* __restrict__ Ab, const bf16* __restrict__ Wt0,
    const bf16* __restrict__ Wt1, const float* __restrict__ bias0,
    const float* __restrict__ bias1, const bf16* __restrict__ oldx,
    void* __restrict__ dstv, const float* __restrict__ skip2)
{
  const int wave = threadIdx.x >> 6, lane = threadIdx.x & 63;
  const int lane15 = lane & 15, quad = lane >> 4;
  const int jc0 = wave * 2;
  const int bid = blockIdx.x;
  const int type = (bid >= GS2);
  const long base = type ? (long)N_STMT * CCH : 0;
  const int Nrows = type ? N_FUNC : N_STMT;
  long row = (long)(type ? bid - GS2 : bid) * RPB2;
  long rowEnd = row + RPB2; if (rowEnd > Nrows) rowEnd = Nrows;
  const bf16* Wt = type ? Wt1 : Wt0;
  const float* bias = type ? bias1 : bias0;

  short8 w[2][4];
#pragma unroll
  for (int jj = 0; jj < 2; jj++)
#pragma unroll
    for (int kq = 0; kq < 4; kq++)
      w[jj][kq] = *(const short8*)(
          Wt + ((jc0 + jj) * 16 + lane15) * CCH + kq * 32 + quad * 8);
  float4 bb[2];
#pragma unroll
  for (int jj = 0; jj < 2; jj++)
    bb[jj] = *(const float4*)(bias + (jc0 + jj) * 16 + quad * 4);

  float g = 1.f, gi = 0.f;
  if (BLEND) {
    float sk = skip2[type];
    g = 1.f / (1.f + expf(-sk));
    gi = 1.f - g;
  }

  // prime first A tile
  short8 a[4];
  {
    long r = row + lane15; if (r >= Nrows) r = Nrows - 1;
#pragma unroll
    for (int kq = 0; kq < 4; kq++)
      a[kq] = *(const short8*)(Ab + base + r * CCH + kq * 32 + quad * 8);
  }

  for (; row < rowEnd; row += 16) {
    short8 an[4];
    {
      long nrow = (row + 16 < rowEnd) ? row + 16 : row;
      long r = nrow + lane15; if (r >= Nrows) r = Nrows - 1;
#pragma unroll
      for (int kq = 0; kq < 4; kq++)
        an[kq] = *(const short8*)(Ab + base + r * CCH + kq * 32 + quad * 8);
    }

    floatx4 acc[2];
#pragma unroll
    for (int jj = 0; jj < 2; jj++) {
      acc[jj][0] = bb[jj].x; acc[jj][1] = bb[jj].y;
      acc[jj][2] = bb[jj].z; acc[jj][3] = bb[jj].w;
    }
#pragma unroll
    for (int kq = 0; kq < 4; kq++)
#pragma unroll
      for (int jj = 0; jj < 2; jj++)
        acc[jj] = __builtin_amdgcn_mfma_f32_16x16x32_bf16(
            w[jj][kq], a[kq], acc[jj], 0, 0, 0);

    long r = row + lane15;
    if (r < Nrows) {
#pragma unroll
      for (int jj = 0; jj < 2; jj++) {
        int c0 = (jc0 + jj) * 16 + quad * 4;
        long idx = base + r * CCH + c0;
        float v[4];
#pragma unroll
        for (int q = 0; q < 4; q++) v[q] = acc[jj][q];
        if (RELU) {
#pragma unroll
          for (int q = 0; q < 4; q++) v[q] = fmaxf(v[q], 0.f);
        }
        if (BLEND) {
          s4v ov = *(const s4v*)(oldx + idx);
#pragma unroll
          for (int q = 0; q < 4; q++) v[q] = g * v[q] + gi * bs2f(ov[q]);
        }
        if (OUT_BF16) {
          s4v o;
#pragma unroll
          for (int q = 0; q < 4; q++) o[q] = f2bs(v[q]);
          *(s4v*)((bf16*)dstv + idx) = o;
        } else {
          float4 o = make_float4(v[0], v[1], v[2], v[3]);
          *(float4*)((float*)dstv + idx) = o;
        }
      }
    }
#pragma unroll
    for (int kq = 0; kq < 4; kq++) a[kq] = an[kq];
  }
}

// ------------ QKV body, register-resident weights, jc-split waves -----------
template <int NM, bool HASQ>
__device__ __forceinline__ void qkv_body(
    const bf16* __restrict__ Ab,
    const bf16* __restrict__ W0, const float* __restrict__ B0,
    const bf16* __restrict__ W1, const float* __restrict__ B1,
    const bf16* __restrict__ W2, const float* __restrict__ B2,
    bf16* __restrict__ Q, bf16* __restrict__ KV, int N, int rpb, int bid)
{
  const int wave = threadIdx.x >> 6, lane = threadIdx.x & 63;
  const int lane15 = lane & 15, quad = lane >> 4;
  const int jc0 = wave * 2;
  constexpr int KIDX = HASQ ? 1 : 0;
  constexpr int VIDX = KIDX + 1;

  long row = (long)bid * rpb;
  if (row >= N) return;
  long rowEnd = row + rpb; if (rowEnd > N) rowEnd = N;

  const bf16* Wm[3]  = {W0, W1, W2};
  const float* Bm[3] = {B0, B1, B2};

  short8 w[NM][2][4];
#pragma unroll
  for (int m = 0; m < NM; m++)
#pragma unroll
    for (int jj = 0; jj < 2; jj++)
#pragma unroll
      for (int kq = 0; kq < 4; kq++)
        w[m][jj][kq] = *(const short8*)(
            Wm[m] + ((jc0 + jj) * 16 + lane15) * CCH + kq * 32 + quad * 8);

  for (; row < rowEnd; row += 16) {
    long r = row + lane15;
    long rc = (r < N) ? r : (N - 1);
    short8 a[4];
#pragma unroll
    for (int kq = 0; kq < 4; kq++)
      a[kq] = *(const short8*)(Ab + rc * CCH + kq * 32 + quad * 8);

    floatx4 acc[NM][2];
#pragma unroll
    for (int m = 0; m < NM; m++)
#pragma unroll
      for (int jj = 0; jj < 2; jj++) {
        float4 bb = *(const float4*)(Bm[m] + (jc0 + jj) * 16 + quad * 4);
        acc[m][jj][0] = bb.x; acc[m][jj][1] = bb.y;
        acc[m][jj][2] = bb.z; acc[m][jj][3] = bb.w;
      }

#pragma unroll
    for (int kq = 0; kq < 4; kq++)
#pragma unroll
      for (int m = 0; m < NM; m++)
#pragma unroll
        for (int jj = 0; jj < 2; jj++)
          acc[m][jj] = __builtin_amdgcn_mfma_f32_16x16x32_bf16(
              w[m][jj][kq], a[kq], acc[m][jj], 0, 0, 0);

    if (r < N) {
#pragma unroll
      for (int jj = 0; jj < 2; jj++) {
        int c0 = (jc0 + jj) * 16 + quad * 4;
        if constexpr (HASQ) {
          s4v qo;
          qo[0] = f2bs(acc[0][jj][0]);
          qo[1] = f2bs(acc[0][jj][1]);
          qo[2] = f2bs(acc[0][jj][2]);
          qo[3] = f2bs(acc[0][jj][3]);
          *(s4v*)(Q + r * CCH + c0) = qo;
        }
        short8 kv;
        kv[0] = f2bs(acc[KIDX][jj][0]);
        kv[1] = f2bs(acc[KIDX][jj][1]);
        kv[2] = f2bs(acc[VIDX][jj][0]);
        kv[3] = f2bs(acc[VIDX][jj][1]);
        kv[4] = f2bs(acc[KIDX][jj][2]);
        kv[5] = f2bs(acc[KIDX][jj][3]);
        kv[6] = f2bs(acc[VIDX][jj][2]);
        kv[7] = f2bs(acc[VIDX][jj][3]);
        *(short8*)(KV + r * 256 + 2 * c0) = kv;
      }
    }
  }
}

// ------ all three QKV GEMMs of one layer in a single dispatch ---------------
__global__ __launch_bounds__(256, 3) void qkv_all(
    const bf16* __restrict__ Xb, const bf16* __restrict__ WT,
    const bf16* __restrict__ WRT, const float* __restrict__ Bf,
    const float* __restrict__ qb,
    bf16* __restrict__ Qb, bf16* __restrict__ KV0,
    bf16* __restrict__ KV1, bf16* __restrict__ KV2, int l)
{
  const int bid = blockIdx.x;
  const int z0 = l * 3 + 0, z1 = l * 3 + 1, z2 = l * 3 + 2;
  if (bid < GA) {
    qkv_body<3, true>(Xb,
        WT + (2 + l * 2) * 16384, qb + (l * 2) * 128,
        WRT + z0 * 16384, Bf + z0 * 128,
        WRT + (6 + z0) * 16384, Bf + (6 + z0) * 128,
        Qb, KV0, N_STMT, 128, bid);
  } else if (bid < GA + GB) {
    qkv_body<2, false>(Xb,
        WRT + z1 * 16384, Bf + z1 * 128,
        WRT + (6 + z1) * 16384, Bf + (6 + z1) * 128,
        nullptr, nullptr,
        nullptr, KV1, N_STMT, 96, bid - GA);
  } else {
    qkv_body<3, true>(Xb + (long)N_STMT * CCH,
        WT + (2 + l * 2 + 1) * 16384, qb + (l * 2 + 1) * 128,
        WRT + z2 * 16384, Bf + z2 * 128,
        WRT + (6 + z2) * 16384, Bf + (6 + z2) * 128,
        Qb + (long)N_STMT * CCH, KV2, N_FUNC, 128, bid - GA - GB);
  }
}

// ---------------- CSR build, all 3 relations per dispatch -------------------
__global__ __launch_bounds__(256) void csr_count_all(
    const int* __restrict__ d0, const int* __restrict__ d1,
    const int* __restrict__ d2, int* __restrict__ degf,
    int* __restrict__ posf)
{
  int r = blockIdx.x / EB;
  int e = (blockIdx.x % EB) * 256 + threadIdx.x;
  if (e < EDGES) {
    const int* dst = r == 0 ? d0 : r == 1 ? d1 : d2;
    int off = r == 0 ? 0 : r == 1 ? 100000 : 150000;
    posf[r * EDGES + e] = atomicAdd(&degf[off + dst[e]], 1);
  }
}
// Grid segmented by relation so the scalar counter address (total + r) is
// wave-uniform -> LLVM atomic optimizer emits DPP wave-scan + 1 atomic/wave.
__global__ __launch_bounds__(256) void csr_alloc_all(
    const int* __restrict__ degf, int* __restrict__ rowstartf,
    int* __restrict__ total)
{
  int bid = blockIdx.x;
  int r, base, Nd, lb;
  if (bid < 391)      { r = 0; base = 0;      Nd = 100000; lb = bid; }
  else if (bid < 587) { r = 1; base = 100000; Nd = 50000;  lb = bid - 391; }
  else                { r = 2; base = 150000; Nd = 100000; lb = bid - 587; }
  int n = lb * 256 + threadIdx.x;
  if (n < Nd) rowstartf[base + n] = atomicAdd(total + r, degf[base + n]);
}
__global__ __launch_bounds__(256) void csr_fill_all(
    const int* __restrict__ d0, const int* __restrict__ d1,
    const int* __restrict__ d2, const int* __restrict__ s0,
    const int* __restrict__ s1, const int* __restrict__ s2,
    const int* __restrict__ rowstartf, const int* __restrict__ posf,
    int* __restrict__ srcs0, int* __restrict__ srcs1, int* __restrict__ srcs2)
{
  int r = blockIdx.x / EB;
  int e = (blockIdx.x % EB) * 256 + threadIdx.x;
  if (e < EDGES) {
    const int* dst = r == 0 ? d0 : r == 1 ? d1 : d2;
    const int* src = r == 0 ? s0 : r == 1 ? s1 : s2;
    int* sr = r == 0 ? srcs0 : r == 1 ? srcs1 : srcs2;
    int off = r == 0 ? 0 : r == 1 ? 100000 : 150000;
    sr[rowstartf[off + dst[e]] + posf[r * EDGES + e]] = src[e];
  }
}

// -------- per-relation message: 16-lane group, serial edges, no merges ------
__device__ __forceinline__ void relmsg_grp(
    int rs, int g, const int* __restrict__ srcs,
    const bf16* __restrict__ KV, float psc,
    const float* __restrict__ q, int lane, float* __restrict__ out)
{
  int p = lane & 15;
  int gbase = lane & 48;                 // first lane of this 16-lane group
  float den = 0.f;
  float a[8] = {0.f,0.f,0.f,0.f,0.f,0.f,0.f,0.f};
  for (int j0 = 0; j0 < g; j0 += 16) {
    int rem = g - j0; if (rem > 16) rem = 16;
    int sl = srcs[rs + j0 + (p < rem ? p : rem - 1)];
    for (int j = 0; j < rem; j++) {
      int s = __shfl(sl, gbase + j);
      const bf16* rowp = KV + (long)s * 256 + 16 * p;
      uint4 u0 = *(const uint4*)(rowp);
      uint4 u1 = *(const uint4*)(rowp + 8);
      float prod = q[0]*blo(u0.x) + q[1]*bhi(u0.x)
                 + q[2]*blo(u0.z) + q[3]*bhi(u0.z)
                 + q[4]*blo(u1.x) + q[5]*bhi(u1.x)
                 + q[6]*blo(u1.z) + q[7]*bhi(u1.z);
      prod += __shfl_xor(prod, 1);
      float ev = __expf(prod * psc);
      den += ev;
      a[0] += ev * blo(u0.y); a[1] += ev * bhi(u0.y);
      a[2] += ev * blo(u0.w); a[3] += ev * bhi(u0.w);
      a[4] += ev * blo(u1.y); a[5] += ev * bhi(u1.y);
      a[6] += ev * blo(u1.w); a[7] += ev * bhi(u1.w);
    }
  }
  float inv = 1.f / (den + 1e-16f);
#pragma unroll
  for (int i = 0; i < 8; i++) out[i] = a[i] * inv;
}

// -------- fused aggregation + GELU: 16 nodes per block (4 per wave) ---------
__global__ __launch_bounds__(256) void agg_all(
    const int* __restrict__ rs0, const int* __restrict__ dg0, const int* __restrict__ srcs0,
    const int* __restrict__ rs1, const int* __restrict__ dg1, const int* __restrict__ srcs1,
    const int* __restrict__ rs2, const int* __restrict__ dg2, const int* __restrict__ srcs2,
    const bf16* __restrict__ KV0, const bf16* __restrict__ KV1,
    const bf16* __restrict__ KV2, const float* __restrict__ pl,
    const bf16* __restrict__ Qb, bf16* __restrict__ AGGb)
{
  int n = blockIdx.x * 16 + (threadIdx.x >> 4);
  if (n >= N_TOT) return;
  int lane = threadIdx.x & 63;
  int p = lane & 15, h = p >> 1;
  uint4 qv = *(const uint4*)(Qb + (long)n * CCH + 8 * p);
  float q[8];
  q[0] = blo(qv.x); q[1] = bhi(qv.x); q[2] = blo(qv.y); q[3] = bhi(qv.y);
  q[4] = blo(qv.z); q[5] = bhi(qv.z); q[6] = blo(qv.w); q[7] = bhi(qv.w);
  float m[8];
  if (n < N_STMT) {
    float m0[8], m2[8];
    relmsg_grp(rs0[n], dg0[n], srcs0, KV0, pl[h] * 0.25f, q, lane, m0);
    relmsg_grp(rs2[n], dg2[n], srcs2, KV2, pl[16 + h] * 0.25f, q, lane, m2);
#pragma unroll
    for (int i = 0; i < 8; i++) m[i] = m0[i] + m2[i];
  } else {
    int nf = n - N_STMT;
    relmsg_grp(rs1[nf], dg1[nf], srcs1, KV1, pl[8 + h] * 0.25f, q, lane, m);
  }
  short8 o;
#pragma unroll
  for (int i = 0; i < 8; i++) o[i] = f2bs(gelu_f(m[i]));
  *(short8*)(AGGb + (long)n * CCH + 8 * p) = o;
}

__global__ __launch_bounds__(256) void zero_out_k(float* __restrict__ out)
{
  long i = ((long)blockIdx.x * 256 + threadIdx.x) * 4;
  *(float4*)(out + i) = make_float4(0.f, 0.f, 0.f, 0.f);
}

extern "C" void kernel_launch(void* const* d_in, const int* in_sizes, int n_in,
                              void* d_out, int out_size, void* d_ws, size_t ws_size,
                              hipStream_t stream)
{
  const int* tok_s = (const int*)d_in[0];
  const int* tok_f = (const int*)d_in[1];
  const int* esrc[3] = {(const int*)d_in[2], (const int*)d_in[4], (const int*)d_in[6]};
  const int* edst[3] = {(const int*)d_in[3], (const int*)d_in[5], (const int*)d_in[7]};
  const float* emb   = (const float*)d_in[8];
  const float* lin_w = (const float*)d_in[9];
  const float* lin_b = (const float*)d_in[10];
  const float* kw = (const float*)d_in[11];
  const float* kb = (const float*)d_in[12];
  const float* qw = (const float*)d_in[13];
  const float* qb = (const float*)d_in[14];
  const float* vw = (const float*)d_in[15];
  const float* vb = (const float*)d_in[16];
  const float* aw = (const float*)d_in[17];
  const float* ab = (const float*)d_in[18];
  const float* skip  = (const float*)d_in[19];
  const float* a_rel = (const float*)d_in[20];
  const float* m_rel = (const float*)d_in[21];
  const float* p_rel = (const float*)d_in[22];

  // ---- ws layout. ----
  float* Bf   = (float*)d_ws;           // 12 x 128 fused biases
  bf16*  Xb   = (bf16*)(Bf + 1536);     // 19,200,000  residual stream
  bf16*  AGGb = Xb  + 19200000L;        // 19,200,000  agg out (alias pooled E)
  bf16*  KV0  = AGGb + 19200000L;       // 25,600,000  stmt r0 KV interleaved
  bf16*  KV1  = KV0 + 25600000L;        // 25,600,000  stmt r1 KV
  bf16*  KV2  = KV1 + 25600000L;        // 12,800,000  func r2 KV
  bf16*  WT   = KV2 + 12800000L;        //    163,840  10 transposed raw mats
  bf16*  WRT  = WT  + 163840L;          //    196,608  12 fused rel mats
  int*   ip   = (int*)(WRT + 196608L);
  int* degf        = ip;                               // 250,000 contiguous
  int* total       = ip + 250000;                      // 4 counters (3 used)
  int* rowstartf   = ip + 250004;                      // 250,000 contiguous
  int* rowstart[3] = {ip + 250004, ip + 350004, ip + 400004};
  int* deg[3]      = {ip, ip + 100000, ip + 150000};
  int* srcs[3]     = {ip + 500004, ip + 700004, ip + 900004};
  int* posf        = ip + 1100004;                     // 3 x 200,000
  bf16* EBF   = KV0;                    // 6,400,000 alias: bf16 emb table,
                                        // dead before KV0 is first written
  bf16*  Qb   = (bf16*)d_out;          // bf16 Q scratch in fp32 d_out,
  float* OUTF = (float*)d_out;         // consumed before epilogue overwrites

  const size_t NEED = (size_t)1536 * 4 + (size_t)102760448 * 2
                    + (size_t)1700004 * 4;
  if (ws_size < NEED) {            // soft-fail diagnostic: absmax == |ref|max
    zero_out_k<<<19200000 / 4 / 256, 256, 0, stream>>>(OUTF);
    return;
  }

  // ---- CSR build: 3 dispatches for all relations ----
  hipMemsetAsync(ip, 0, (size_t)250004 * 4, stream);
  csr_count_all<<<3 * EB, 256, 0, stream>>>(
      edst[0], edst[1], edst[2], degf, posf);
  csr_alloc_all<<<978, 256, 0, stream>>>(degf, rowstartf, total);
  csr_fill_all<<<3 * EB, 256, 0, stream>>>(
      edst[0], edst[1], edst[2], esrc[0], esrc[1], esrc[2],
      rowstartf, posf, srcs[0], srcs[1], srcs[2]);

  // ---- one-time prep (emb2bf + transp_w + make_wr_all) ----
  prep_all<<<4533, 256, 0, stream>>>(
      emb, EBF, lin_w, qw, aw, WT, kw, kb, vw, vb, a_rel, m_rel, WRT, Bf);

  // ---- prologue: pooled embeddings -> fused per-type linear+relu -> Xb ----
  pool_embed<<<N_TOT / 4, 256, 0, stream>>>(tok_s, tok_f, EBF, AGGb);
  gemm_2t_reg<true, false, true><<<GS2 + GF2, 256, 0, stream>>>(
      AGGb, WT, WT + 16384, lin_b, lin_b + 128, nullptr, Xb, nullptr);

  for (int l = 0; l < 2; l++) {
    // all three QKV GEMMs in one dispatch
    qkv_all<<<GA + GB + GF, 256, 0, stream>>>(
        Xb, WT, WRT, Bf, qb, Qb, KV0, KV1, KV2, l);
    // fused aggregation (+GELU) over all nodes, 16 nodes/block
    agg_all<<<(N_TOT + 15) / 16, 256, 0, stream>>>(
        rowstart[0], deg[0], srcs[0], rowstart[1], deg[1], srcs[1],
        rowstart[2], deg[2], srcs[2], KV0, KV1, KV2,
        p_rel + l * 24, Qb, AGGb);
    // fused out-proj + gated skip blend. l=0 -> Xb; l=1 -> fp32 d_out.
    if (l == 0)
      gemm_2t_reg<false, true, true><<<GS2 + GF2, 256, 0, stream>>>(
          AGGb, WT + 6 * 16384, WT + 7 * 16384, ab, ab + 128,
          Xb, Xb, skip);
    else
      gemm_2t_reg<false, true, false><<<GS2 + GF2, 256, 0, stream>>>(
          AGGb, WT + 8 * 16384, WT + 9 * 16384, ab + 256, ab + 384,
          Xb, OUTF, skip + 2);
  }
}

// Round 15
// 666.139 us; speedup vs baseline: 5.2171x; 1.0196x over previous
//
#include <hip/hip_runtime.h>
#include <hip/hip_bf16.h>

// HGT forward, MI355X. Round 20: prologue dispatch fusion (6 -> 3).
// R19 post-mortem: csr_alloc fix confirmed (2836us -> gone), wall 679us
// (best). qkv_all 83us x2 at occ 24% / 2.5 TB/s / writes ~= ideal -> at its
// occupancy-BW limit (reg-capped 3 waves/SIMD); no cheap win inside it.
// This round: harvest remaining launch gaps. Dependency structure allows
// (prep||count) -> (pool||alloc) -> (2t-prologue||fill): 3 branch-on-blockIdx
// mega-dispatches replace 6 serial ones; small CSR grids fill CUs during big
// kernels' ramp/drain. gemm_2t_reg refactored to shared __device__ body.
// Decision rule: gain <15us -> gaps exhausted, fuse agg+out-proj next.

typedef __hip_bfloat16 bf16;
typedef __attribute__((ext_vector_type(8))) short short8;
typedef __attribute__((ext_vector_type(4))) short s4v;
typedef __attribute__((ext_vector_type(4))) float floatx4;

#define N_STMT 100000
#define N_FUNC 50000
#define N_TOT  150000
#define EDGES  200000
#define CCH 128
#define RPB2 96    // rows/block, 2t kernels (6 iters of 16)
#define GS2 1042   // ceil(100000/96)
#define GF2 521    // ceil(50000/96)
#define GA 782     // ceil(100000/128) stmt A blocks (NM=3, rpb=128)
#define GB 1042    // ceil(100000/96)  stmt B blocks (NM=2, rpb=96)
#define GF 391     // ceil(50000/128)  func blocks   (NM=3, rpb=128)
#define EB 782     // ceil(EDGES/256)
#define PREPB 4533 // prep blocks (3125 emb2bf + 640 transp + 768 make_wr)
#define POOLB 37500

__device__ __forceinline__ float b2f(bf16 x){ return __bfloat162float(x); }
__device__ __forceinline__ float bs2f(short s){
  union { short s; bf16 h; } u; u.s = s; return __bfloat162float(u.h);
}
__device__ __forceinline__ short f2bs(float x){
  union { bf16 h; short s; } u; u.h = __float2bfloat16(x); return u.s;
}
__device__ __forceinline__ float blo(unsigned u){ return __uint_as_float(u << 16); }
__device__ __forceinline__ float bhi(unsigned u){ return __uint_as_float(u & 0xffff0000u); }
// tanh-form gelu via single exp: 0.5x(1+tanh(u)) = x - x/(e^{2u}+1)
__device__ __forceinline__ float gelu_f(float x){
  float z = 1.5957691216057308f * (x + 0.044715f * x * x * x);
  float t = __expf(z);
  return x - x / (t + 1.f);
}

// ================= device bodies =================

__device__ __forceinline__ void prep_body(
    int bid, const float* __restrict__ emb, bf16* __restrict__ ebf,
    const float* __restrict__ lin_w, const float* __restrict__ qw,
    const float* __restrict__ aw, bf16* __restrict__ WT,
    const float* __restrict__ kw, const float* __restrict__ kb,
    const float* __restrict__ vw, const float* __restrict__ vb,
    const float* __restrict__ a_rel, const float* __restrict__ m_rel,
    bf16* __restrict__ WRT, float* __restrict__ Bf)
{
  if (bid < 3125) {
    long i = ((long)bid * 256 + threadIdx.x) * 8;
    float4 f0 = *(const float4*)(emb + i);
    float4 f1 = *(const float4*)(emb + i + 4);
    short8 o;
    o[0]=f2bs(f0.x); o[1]=f2bs(f0.y); o[2]=f2bs(f0.z); o[3]=f2bs(f0.w);
    o[4]=f2bs(f1.x); o[5]=f2bs(f1.y); o[6]=f2bs(f1.z); o[7]=f2bs(f1.w);
    *(short8*)(ebf + i) = o;
  } else if (bid < 3765) {
    int lb = bid - 3125;
    int mat = lb >> 6;
    const float* src = (mat < 2) ? lin_w + mat * 16384
                     : (mat < 6) ? qw + (mat - 2) * 16384
                                 : aw + (mat - 6) * 16384;
    bf16* dst = WT + mat * 16384;
    int idx = (lb & 63) * 256 + threadIdx.x;     // n*128+k
    int n = idx >> 7, k = idx & 127;
    dst[idx] = __float2bfloat16(src[k * 128 + n]);
  } else {
    int lb = bid - 3765;
    int y = lb >> 6;
    bool isV = y >= 6;
    int z = isV ? y - 6 : y;
    int l = z / 3, r = z % 3, st = (r == 2) ? 1 : 0;
    const float* W   = (isV ? vw : kw) + (l * 2 + st) * 16384;
    const float* b   = (isV ? vb : kb) + (l * 2 + st) * 128;
    const float* rel = (isV ? m_rel : a_rel) + z * 2048;
    bf16* Wrt = WRT + y * 16384;
    float* br = Bf + y * 128;

    int idx = (lb & 63) * 256 + threadIdx.x;
    if (idx < 128 * 128) {
      int c = idx >> 7, o = idx & 127;
      int h = o >> 4, e = o & 15;
      float acc = 0.f;
#pragma unroll
      for (int d = 0; d < 16; d++)
        acc += W[c * 128 + h * 16 + d] * rel[h * 256 + d * 16 + e];
      Wrt[o * 128 + c] = __float2bfloat16(acc);
    }
    if (idx < 128) {
      int h = idx >> 4, e = idx & 15;
      float acc = 0.f;
#pragma unroll
      for (int d = 0; d < 16; d++)
        acc += b[h * 16 + d] * rel[h * 256 + d * 16 + e];
      br[idx] = acc;
    }
  }
}

__device__ __forceinline__ void pool_body(
    int bid, const int* __restrict__ tok_s, const int* __restrict__ tok_f,
    const bf16* __restrict__ ebf, bf16* __restrict__ E_out)
{
  int n = bid * 4 + (threadIdx.x >> 6);
  int lane = threadIdx.x & 63, g = lane >> 4, c16 = lane & 15;
  const int* tok = (n < N_STMT) ? (tok_s + n * 16) : (tok_f + (n - N_STMT) * 16);
  float acc[8] = {0.f,0.f,0.f,0.f,0.f,0.f,0.f,0.f};
#pragma unroll
  for (int j = 0; j < 4; j++) {
    int v = tok[g * 4 + j];
    short8 row = *(const short8*)(ebf + (long)v * CCH + c16 * 8);
#pragma unroll
    for (int q = 0; q < 8; q++) acc[q] += bs2f(row[q]);
  }
#pragma unroll
  for (int q = 0; q < 8; q++) {
    acc[q] += __shfl_xor(acc[q], 16);
    acc[q] += __shfl_xor(acc[q], 32);
  }
  if (g == 0) {
    short8 o;
#pragma unroll
    for (int q = 0; q < 8; q++) o[q] = f2bs(fmaxf(acc[q] * (1.f/16.f), 0.f));
    *(short8*)(E_out + (long)n * CCH + c16 * 8) = o;
  }
}

// 2-type GEMM body, register-resident weights, pipelined A.
template <bool RELU, bool BLEND, bool OUT_BF16>
__device__ __forceinline__ void gemm_2t_body(
    int bid, const bf16* __restrict__ Ab, const bf16* __restrict__ Wt0,
    const bf16* __restrict__ Wt1, const float* __restrict__ bias0,
    const float* __restrict__ bias1, const bf16* __restrict__ oldx,
    void* __restrict__ dstv, const float* __restrict__ skip2)
{
  const int wave = threadIdx.x >> 6, lane = threadIdx.x & 63;
  const int lane15 = lane & 15, quad = lane >> 4;
  const int jc0 = wave * 2;
  const int type = (bid >= GS2);
  const long base = type ? (long)N_STMT * CCH : 0;
  const int Nrows = type ? N_FUNC : N_STMT;
  long row = (long)(type ? bid - GS2 : bid) * RPB2;
  long rowEnd = row + RPB2; if (rowEnd > Nrows) rowEnd = Nrows;
  const bf16* Wt = type ? Wt1 : Wt0;
  const float* bias = type ? bias1 : bias0;

  short8 w[2][4];
#pragma unroll
  for (int jj = 0; jj < 2; jj++)
#pragma unroll
    for (int kq = 0; kq < 4; kq++)
      w[jj][kq] = *(const short8*)(
          Wt + ((jc0 + jj) * 16 + lane15) * CCH + kq * 32 + quad * 8);
  float4 bb[2];
#pragma unroll
  for (int jj = 0; jj < 2; jj++)
    bb[jj] = *(const float4*)(bias + (jc0 + jj) * 16 + quad * 4);

  float g = 1.f, gi = 0.f;
  if (BLEND) {
    float sk = skip2[type];
    g = 1.f / (1.f + expf(-sk));
    gi = 1.f - g;
  }

  // prime first A tile
  short8 a[4];
  {
    long r = row + lane15; if (r >= Nrows) r = Nrows - 1;
#pragma unroll
    for (int kq = 0; kq < 4; kq++)
      a[kq] = *(const short8*)(Ab + base + r * CCH + kq * 32 + quad * 8);
  }

  for (; row < rowEnd; row += 16) {
    short8 an[4];
    {
      long nrow = (row + 16 < rowEnd) ? row + 16 : row;
      long r = nrow + lane15; if (r >= Nrows) r = Nrows - 1;
#pragma unroll
      for (int kq = 0; kq < 4; kq++)
        an[kq] = *(const short8*)(Ab + base + r * CCH + kq * 32 + quad * 8);
    }

    floatx4 acc[2];
#pragma unroll
    for (int jj = 0; jj < 2; jj++) {
      acc[jj][0] = bb[jj].x; acc[jj][1] = bb[jj].y;
      acc[jj][2] = bb[jj].z; acc[jj][3] = bb[jj].w;
    }
#pragma unroll
    for (int kq = 0; kq < 4; kq++)
#pragma unroll
      for (int jj = 0; jj < 2; jj++)
        acc[jj] = __builtin_amdgcn_mfma_f32_16x16x32_bf16(
            w[jj][kq], a[kq], acc[jj], 0, 0, 0);

    long r = row + lane15;
    if (r < Nrows) {
#pragma unroll
      for (int jj = 0; jj < 2; jj++) {
        int c0 = (jc0 + jj) * 16 + quad * 4;
        long idx = base + r * CCH + c0;
        float v[4];
#pragma unroll
        for (int q = 0; q < 4; q++) v[q] = acc[jj][q];
        if (RELU) {
#pragma unroll
          for (int q = 0; q < 4; q++) v[q] = fmaxf(v[q], 0.f);
        }
        if (BLEND) {
          s4v ov = *(const s4v*)(oldx + idx);
#pragma unroll
          for (int q = 0; q < 4; q++) v[q] = g * v[q] + gi * bs2f(ov[q]);
        }
        if (OUT_BF16) {
          s4v o;
#pragma unroll
          for (int q = 0; q < 4; q++) o[q] = f2bs(v[q]);
          *(s4v*)((bf16*)dstv + idx) = o;
        } else {
          float4 o = make_float4(v[0], v[1], v[2], v[3]);
          *(float4*)((float*)dstv + idx) = o;
        }
      }
    }
#pragma unroll
    for (int kq = 0; kq < 4; kq++) a[kq] = an[kq];
  }
}

// ================= fused front dispatches =================

// front1: prep (PREPB blocks) || csr_count (3*EB blocks)
__global__ __launch_bounds__(256) void front1(
    const float* __restrict__ emb, bf16* __restrict__ ebf,
    const float* __restrict__ lin_w, const float* __restrict__ qw,
    const float* __restrict__ aw, bf16* __restrict__ WT,
    const float* __restrict__ kw, const float* __restrict__ kb,
    const float* __restrict__ vw, const float* __restrict__ vb,
    const float* __restrict__ a_rel, const float* __restrict__ m_rel,
    bf16* __restrict__ WRT, float* __restrict__ Bf,
    const int* __restrict__ d0, const int* __restrict__ d1,
    const int* __restrict__ d2, int* __restrict__ degf,
    int* __restrict__ posf)
{
  int bid = blockIdx.x;
  if (bid < PREPB) {
    prep_body(bid, emb, ebf, lin_w, qw, aw, WT, kw, kb, vw, vb,
              a_rel, m_rel, WRT, Bf);
  } else {
    int lb = bid - PREPB;
    int r = lb / EB;
    int e = (lb % EB) * 256 + threadIdx.x;
    if (e < EDGES) {
      const int* dst = r == 0 ? d0 : r == 1 ? d1 : d2;
      int off = r == 0 ? 0 : r == 1 ? 100000 : 150000;
      posf[r * EDGES + e] = atomicAdd(&degf[off + dst[e]], 1);
    }
  }
}

// front2: pool (POOLB blocks) || csr_alloc (978 blocks, relation-segmented so
// the counter address is wave-uniform -> DPP wave-scan + 1 atomic/wave)
__global__ __launch_bounds__(256) void front2(
    const int* __restrict__ tok_s, const int* __restrict__ tok_f,
    const bf16* __restrict__ ebf, bf16* __restrict__ E_out,
    const int* __restrict__ degf, int* __restrict__ rowstartf,
    int* __restrict__ total)
{
  int bid = blockIdx.x;
  if (bid < POOLB) {
    pool_body(bid, tok_s, tok_f, ebf, E_out);
  } else {
    int lb = bid - POOLB;
    int r, base, Nd, b2;
    if (lb < 391)      { r = 0; base = 0;      Nd = 100000; b2 = lb; }
    else if (lb < 587) { r = 1; base = 100000; Nd = 50000;  b2 = lb - 391; }
    else               { r = 2; base = 150000; Nd = 100000; b2 = lb - 587; }
    int n = b2 * 256 + threadIdx.x;
    if (n < Nd) rowstartf[base + n] = atomicAdd(total + r, degf[base + n]);
  }
}

// front3: prologue linear (GS2+GF2 blocks) || csr_fill (3*EB blocks)
__global__ __launch_bounds__(256) void front3(
    const bf16* __restrict__ Ab, const bf16* __restrict__ Wt0,
    const bf16* __restrict__ Wt1, const float* __restrict__ bias0,
    const float* __restrict__ bias1, bf16* __restrict__ Xb,
    const int* __restrict__ d0, const int* __restrict__ d1,
    const int* __restrict__ d2, const int* __restrict__ s0,
    const int* __restrict__ s1, const int* __restrict__ s2,
    const int* __restrict__ rowstartf, const int* __restrict__ posf,
    int* __restrict__ srcs0, int* __restrict__ srcs1, int* __restrict__ srcs2)
{
  int bid = blockIdx.x;
  if (bid < GS2 + GF2) {
    gemm_2t_body<true, false, true>(bid, Ab, Wt0, Wt1, bias0, bias1,
                                    nullptr, Xb, nullptr);
  } else {
    int lb = bid - (GS2 + GF2);
    int r = lb / EB;
    int e = (lb % EB) * 256 + threadIdx.x;
    if (e < EDGES) {
      const int* dst = r == 0 ? d0 : r == 1 ? d1 : d2;
      const int* src = r == 0 ? s0 : r == 1 ? s1 : s2;
      int* sr = r == 0 ? srcs0 : r == 1 ? srcs1 : srcs2;
      int off = r == 0 ? 0 : r == 1 ? 100000 : 150000;
      sr[rowstartf[off + dst[e]] + posf[r * EDGES + e]] = src[e];
    }
  }
}

// ================= main-loop kernels =================

// out-proj + gated skip blend (standalone)
template <bool RELU, bool BLEND, bool OUT_BF16>
__global__ __launch_bounds__(256) void gemm_2t_reg(
    const bf16* __restrict__ Ab, const bf16* __restrict__ Wt0,
    const bf16* __restrict__ Wt1, const float* __restrict__ bias0,
    const float* __restrict__ bias1, const bf16* __restrict__ oldx,
    void* __restrict__ dstv, const float* __restrict__ skip2)
{
  gemm_2t_body<RELU, BLEND, OUT_BF16>(blockIdx.x, Ab, Wt0, Wt1, bias0, bias1,
                                      oldx, dstv, skip2);
}

// QKV body, register-resident weights, jc-split waves
template <int NM, bool HASQ>
__device__ __forceinline__ void qkv_body(
    const bf16* __restrict__ Ab,
    const bf16* __restrict__ W0, const float* __restrict__ B0,
    const bf16* __restrict__ W1, const float* __restrict__ B1,
    const bf16* __restrict__ W2, const float* __restrict__ B2,
    bf16* __restrict__ Q, bf16* __restrict__ KV, int N, int rpb, int bid)
{
  const int wave = threadIdx.x >> 6, lane = threadIdx.x & 63;
  const int lane15 = lane & 15, quad = lane >> 4;
  const int jc0 = wave * 2;
  constexpr int KIDX = HASQ ? 1 : 0;
  constexpr int VIDX = KIDX + 1;

  long row = (long)bid * rpb;
  if (row >= N) return;
  long rowEnd = row + rpb; if (rowEnd > N) rowEnd = N;

  const bf16* Wm[3]  = {W0, W1, W2};
  const float* Bm[3] = {B0, B1, B2};

  short8 w[NM][2][4];
#pragma unroll
  for (int m = 0; m < NM; m++)
#pragma unroll
    for (int jj = 0; jj < 2; jj++)
#pragma unroll
      for (int kq = 0; kq < 4; kq++)
        w[m][jj][kq] = *(const short8*)(
            Wm[m] + ((jc0 + jj) * 16 + lane15) * CCH + kq * 32 + quad * 8);

  for (; row < rowEnd; row += 16) {
    long r = row + lane15;
    long rc = (r < N) ? r : (N - 1);
    short8 a[4];
#pragma unroll
    for (int kq = 0; kq < 4; kq++)
      a[kq] = *(const short8*)(Ab + rc * CCH + kq * 32 + quad * 8);

    floatx4 acc[NM][2];
#pragma unroll
    for (int m = 0; m < NM; m++)
#pragma unroll
      for (int jj = 0; jj < 2; jj++) {
        float4 bb = *(const float4*)(Bm[m] + (jc0 + jj) * 16 + quad * 4);
        acc[m][jj][0] = bb.x; acc[m][jj][1] = bb.y;
        acc[m][jj][2] = bb.z; acc[m][jj][3] = bb.w;
      }

#pragma unroll
    for (int kq = 0; kq < 4; kq++)
#pragma unroll
      for (int m = 0; m < NM; m++)
#pragma unroll
        for (int jj = 0; jj < 2; jj++)
          acc[m][jj] = __builtin_amdgcn_mfma_f32_16x16x32_bf16(
              w[m][jj][kq], a[kq], acc[m][jj], 0, 0, 0);

    if (r < N) {
#pragma unroll
      for (int jj = 0; jj < 2; jj++) {
        int c0 = (jc0 + jj) * 16 + quad * 4;
        if constexpr (HASQ) {
          s4v qo;
          qo[0] = f2bs(acc[0][jj][0]);
          qo[1] = f2bs(acc[0][jj][1]);
          qo[2] = f2bs(acc[0][jj][2]);
          qo[3] = f2bs(acc[0][jj][3]);
          *(s4v*)(Q + r * CCH + c0) = qo;
        }
        short8 kv;
        kv[0] = f2bs(acc[KIDX][jj][0]);
        kv[1] = f2bs(acc[KIDX][jj][1]);
        kv[2] = f2bs(acc[VIDX][jj][0]);
        kv[3] = f2bs(acc[VIDX][jj][1]);
        kv[4] = f2bs(acc[KIDX][jj][2]);
        kv[5] = f2bs(acc[KIDX][jj][3]);
        kv[6] = f2bs(acc[VIDX][jj][2]);
        kv[7] = f2bs(acc[VIDX][jj][3]);
        *(short8*)(KV + r * 256 + 2 * c0) = kv;
      }
    }
  }
}

// all three QKV GEMMs of one layer in a single dispatch
__global__ __launch_bounds__(256, 3) void qkv_all(
    const bf16* __restrict__ Xb, const bf16* __restrict__ WT,
    const bf16* __restrict__ WRT, const float* __restrict__ Bf,
    const float* __restrict__ qb,
    bf16* __restrict__ Qb, bf16* __restrict__ KV0,
    bf16* __restrict__ KV1, bf16* __restrict__ KV2, int l)
{
  const int bid = blockIdx.x;
  const int z0 = l * 3 + 0, z1 = l * 3 + 1, z2 = l * 3 + 2;
  if (bid < GA) {
    qkv_body<3, true>(Xb,
        WT + (2 + l * 2) * 16384, qb + (l * 2) * 128,
        WRT + z0 * 16384, Bf + z0 * 128,
        WRT + (6 + z0) * 16384, Bf + (6 + z0) * 128,
        Qb, KV0, N_STMT, 128, bid);
  } else if (bid < GA + GB) {
    qkv_body<2, false>(Xb,
        WRT + z1 * 16384, Bf + z1 * 128,
        WRT + (6 + z1) * 16384, Bf + (6 + z1) * 128,
        nullptr, nullptr,
        nullptr, KV1, N_STMT, 96, bid - GA);
  } else {
    qkv_body<3, true>(Xb + (long)N_STMT * CCH,
        WT + (2 + l * 2 + 1) * 16384, qb + (l * 2 + 1) * 128,
        WRT + z2 * 16384, Bf + z2 * 128,
        WRT + (6 + z2) * 16384, Bf + (6 + z2) * 128,
        Qb + (long)N_STMT * CCH, KV2, N_FUNC, 128, bid - GA - GB);
  }
}

// -------- per-relation message: 16-lane group, serial edges, no merges ------
__device__ __forceinline__ void relmsg_grp(
    int rs, int g, const int* __restrict__ srcs,
    const bf16* __restrict__ KV, float psc,
    const float* __restrict__ q, int lane, float* __restrict__ out)
{
  int p = lane & 15;
  int gbase = lane & 48;                 // first lane of this 16-lane group
  float den = 0.f;
  float a[8] = {0.f,0.f,0.f,0.f,0.f,0.f,0.f,0.f};
  for (int j0 = 0; j0 < g; j0 += 16) {
    int rem = g - j0; if (rem > 16) rem = 16;
    int sl = srcs[rs + j0 + (p < rem ? p : rem - 1)];
    for (int j = 0; j < rem; j++) {
      int s = __shfl(sl, gbase + j);
      const bf16* rowp = KV + (long)s * 256 + 16 * p;
      uint4 u0 = *(const uint4*)(rowp);
      uint4 u1 = *(const uint4*)(rowp + 8);
      float prod = q[0]*blo(u0.x) + q[1]*bhi(u0.x)
                 + q[2]*blo(u0.z) + q[3]*bhi(u0.z)
                 + q[4]*blo(u1.x) + q[5]*bhi(u1.x)
                 + q[6]*blo(u1.z) + q[7]*bhi(u1.z);
      prod += __shfl_xor(prod, 1);
      float ev = __expf(prod * psc);
      den += ev;
      a[0] += ev * blo(u0.y); a[1] += ev * bhi(u0.y);
      a[2] += ev * blo(u0.w); a[3] += ev * bhi(u0.w);
      a[4] += ev * blo(u1.y); a[5] += ev * bhi(u1.y);
      a[6] += ev * blo(u1.w); a[7] += ev * bhi(u1.w);
    }
  }
  float inv = 1.f / (den + 1e-16f);
#pragma unroll
  for (int i = 0; i < 8; i++) out[i] = a[i] * inv;
}

// -------- fused aggregation + GELU: 16 nodes per block (4 per wave) ---------
__global__ __launch_bounds__(256) void agg_all(
    const int* __restrict__ rs0, const int* __restrict__ dg0, const int* __restrict__ srcs0,
    const int* __restrict__ rs1, const int* __restrict__ dg1, const int* __restrict__ srcs1,
    const int* __restrict__ rs2, const int* __restrict__ dg2, const int* __restrict__ srcs2,
    const bf16* __restrict__ KV0, const bf16* __restrict__ KV1,
    const bf16* __restrict__ KV2, const float* __restrict__ pl,
    const bf16* __restrict__ Qb, bf16* __restrict__ AGGb)
{
  int n = blockIdx.x * 16 + (threadIdx.x >> 4);
  if (n >= N_TOT) return;
  int lane = threadIdx.x & 63;
  int p = lane & 15, h = p >> 1;
  uint4 qv = *(const uint4*)(Qb + (long)n * CCH + 8 * p);
  float q[8];
  q[0] = blo(qv.x); q[1] = bhi(qv.x); q[2] = blo(qv.y); q[3] = bhi(qv.y);
  q[4] = blo(qv.z); q[5] = bhi(qv.z); q[6] = blo(qv.w); q[7] = bhi(qv.w);
  float m[8];
  if (n < N_STMT) {
    float m0[8], m2[8];
    relmsg_grp(rs0[n], dg0[n], srcs0, KV0, pl[h] * 0.25f, q, lane, m0);
    relmsg_grp(rs2[n], dg2[n], srcs2, KV2, pl[16 + h] * 0.25f, q, lane, m2);
#pragma unroll
    for (int i = 0; i < 8; i++) m[i] = m0[i] + m2[i];
  } else {
    int nf = n - N_STMT;
    relmsg_grp(rs1[nf], dg1[nf], srcs1, KV1, pl[8 + h] * 0.25f, q, lane, m);
  }
  short8 o;
#pragma unroll
  for (int i = 0; i < 8; i++) o[i] = f2bs(gelu_f(m[i]));
  *(short8*)(AGGb + (long)n * CCH + 8 * p) = o;
}

__global__ __launch_bounds__(256) void zero_out_k(float* __restrict__ out)
{
  long i = ((long)blockIdx.x * 256 + threadIdx.x) * 4;
  *(float4*)(out + i) = make_float4(0.f, 0.f, 0.f, 0.f);
}

extern "C" void kernel_launch(void* const* d_in, const int* in_sizes, int n_in,
                              void* d_out, int out_size, void* d_ws, size_t ws_size,
                              hipStream_t stream)
{
  const int* tok_s = (const int*)d_in[0];
  const int* tok_f = (const int*)d_in[1];
  const int* esrc[3] = {(const int*)d_in[2], (const int*)d_in[4], (const int*)d_in[6]};
  const int* edst[3] = {(const int*)d_in[3], (const int*)d_in[5], (const int*)d_in[7]};
  const float* emb   = (const float*)d_in[8];
  const float* lin_w = (const float*)d_in[9];
  const float* lin_b = (const float*)d_in[10];
  const float* kw = (const float*)d_in[11];
  const float* kb = (const float*)d_in[12];
  const float* qw = (const float*)d_in[13];
  const float* qb = (const float*)d_in[14];
  const float* vw = (const float*)d_in[15];
  const float* vb = (const float*)d_in[16];
  const float* aw = (const float*)d_in[17];
  const float* ab = (const float*)d_in[18];
  const float* skip  = (const float*)d_in[19];
  const float* a_rel = (const float*)d_in[20];
  const float* m_rel = (const float*)d_in[21];
  const float* p_rel = (const float*)d_in[22];

  // ---- ws layout. ----
  float* Bf   = (float*)d_ws;           // 12 x 128 fused biases
  bf16*  Xb   = (bf16*)(Bf + 1536);     // 19,200,000  residual stream
  bf16*  AGGb = Xb  + 19200000L;        // 19,200,000  agg out (alias pooled E)
  bf16*  KV0  = AGGb + 19200000L;       // 25,600,000  stmt r0 KV interleaved
  bf16*  KV1  = KV0 + 25600000L;        // 25,600,000  stmt r1 KV
  bf16*  KV2  = KV1 + 25600000L;        // 12,800,000  func r2 KV
  bf16*  WT   = KV2 + 12800000L;        //    163,840  10 transposed raw mats
  bf16*  WRT  = WT  + 163840L;          //    196,608  12 fused rel mats
  int*   ip   = (int*)(WRT + 196608L);
  int* degf        = ip;                               // 250,000 contiguous
  int* total       = ip + 250000;                      // 4 counters (3 used)
  int* rowstartf   = ip + 250004;                      // 250,000 contiguous
  int* rowstart[3] = {ip + 250004, ip + 350004, ip + 400004};
  int* deg[3]      = {ip, ip + 100000, ip + 150000};
  int* srcs[3]     = {ip + 500004, ip + 700004, ip + 900004};
  int* posf        = ip + 1100004;                     // 3 x 200,000
  bf16* EBF   = KV0;                    // 6,400,000 alias: bf16 emb table,
                                        // dead before KV0 is first written
  bf16*  Qb   = (bf16*)d_out;          // bf16 Q scratch in fp32 d_out,
  float* OUTF = (float*)d_out;         // consumed before epilogue overwrites

  const size_t NEED = (size_t)1536 * 4 + (size_t)102760448 * 2
                    + (size_t)1700004 * 4;
  if (ws_size < NEED) {            // soft-fail diagnostic: absmax == |ref|max
    zero_out_k<<<19200000 / 4 / 256, 256, 0, stream>>>(OUTF);
    return;
  }

  // ---- fused front: (prep || count) -> (pool || alloc) -> (lin || fill) ----
  hipMemsetAsync(ip, 0, (size_t)250004 * 4, stream);
  front1<<<PREPB + 3 * EB, 256, 0, stream>>>(
      emb, EBF, lin_w, qw, aw, WT, kw, kb, vw, vb, a_rel, m_rel, WRT, Bf,
      edst[0], edst[1], edst[2], degf, posf);
  front2<<<POOLB + 978, 256, 0, stream>>>(
      tok_s, tok_f, EBF, AGGb, degf, rowstartf, total);
  front3<<<GS2 + GF2 + 3 * EB, 256, 0, stream>>>(
      AGGb, WT, WT + 16384, lin_b, lin_b + 128, Xb,
      edst[0], edst[1], edst[2], esrc[0], esrc[1], esrc[2],
      rowstartf, posf, srcs[0], srcs[1], srcs[2]);

  for (int l = 0; l < 2; l++) {
    // all three QKV GEMMs in one dispatch
    qkv_all<<<GA + GB + GF, 256, 0, stream>>>(
        Xb, WT, WRT, Bf, qb, Qb, KV0, KV1, KV2, l);
    // fused aggregation (+GELU) over all nodes, 16 nodes/block
    agg_all<<<(N_TOT + 15) / 16, 256, 0, stream>>>(
        rowstart[0], deg[0], srcs[0], rowstart[1], deg[1], srcs[1],
        rowstart[2], deg[2], srcs[2], KV0, KV1, KV2,
        p_rel + l * 24, Qb, AGGb);
    // fused out-proj + gated skip blend. l=0 -> Xb; l=1 -> fp32 d_out.
    if (l == 0)
      gemm_2t_reg<false, true, true><<<GS2 + GF2, 256, 0, stream>>>(
          AGGb, WT + 6 * 16384, WT + 7 * 16384, ab, ab + 128,
          Xb, Xb, skip);
    else
      gemm_2t_reg<false, true, false><<<GS2 + GF2, 256, 0, stream>>>(
          AGGb, WT + 8 * 16384, WT + 9 * 16384, ab + 256, ab + 384,
          Xb, OUTF, skip + 2);
  }
}

// Round 16
// 630.494 us; speedup vs baseline: 5.5120x; 1.0565x over previous
//
#include <hip/hip_runtime.h>
#include <hip/hip_bf16.h>

// HGT forward, MI355X. Round 21: front2 grid reorder + block-level alloc.
// R20 post-mortem: fusion gained 13us but front2 = 110us vs pool's 66
// standalone (same 217MB FETCH, BW 3.9->2.4 TB/s): alloc blocks appended at
// grid END ran AFTER pool drained -> serial sum, and alloc itself ~44us
// (3.9k wave-scanned same-line L2 atomics, ~100+cy serialized/counter).
// Fix: (1) put latency-serialized small blocks FIRST in each front grid
// (alloc/count/fill) so they overlap the big kernel instead of trailing it;
// (2) alloc uses LDS+shfl-up block scan -> ONE atomic per block (978 total,
// ~326/counter) with exclusive prefix distributed in-block. Segments stay
// disjoint/contiguous per dst (ordering already arbitrary). Rest unchanged.

typedef __hip_bfloat16 bf16;
typedef __attribute__((ext_vector_type(8))) short short8;
typedef __attribute__((ext_vector_type(4))) short s4v;
typedef __attribute__((ext_vector_type(4))) float floatx4;

#define N_STMT 100000
#define N_FUNC 50000
#define N_TOT  150000
#define EDGES  200000
#define CCH 128
#define RPB2 96    // rows/block, 2t kernels (6 iters of 16)
#define GS2 1042   // ceil(100000/96)
#define GF2 521    // ceil(50000/96)
#define GA 782     // ceil(100000/128) stmt A blocks (NM=3, rpb=128)
#define GB 1042    // ceil(100000/96)  stmt B blocks (NM=2, rpb=96)
#define GF 391     // ceil(50000/128)  func blocks   (NM=3, rpb=128)
#define EB 782     // ceil(EDGES/256)
#define PREPB 4533 // prep blocks (3125 emb2bf + 640 transp + 768 make_wr)
#define POOLB 37500
#define ALLOCB 978 // alloc blocks (391 r0 + 196 r1 + 391 r2)

__device__ __forceinline__ float b2f(bf16 x){ return __bfloat162float(x); }
__device__ __forceinline__ float bs2f(short s){
  union { short s; bf16 h; } u; u.s = s; return __bfloat162float(u.h);
}
__device__ __forceinline__ short f2bs(float x){
  union { bf16 h; short s; } u; u.h = __float2bfloat16(x); return u.s;
}
__device__ __forceinline__ float blo(unsigned u){ return __uint_as_float(u << 16); }
__device__ __forceinline__ float bhi(unsigned u){ return __uint_as_float(u & 0xffff0000u); }
// tanh-form gelu via single exp: 0.5x(1+tanh(u)) = x - x/(e^{2u}+1)
__device__ __forceinline__ float gelu_f(float x){
  float z = 1.5957691216057308f * (x + 0.044715f * x * x * x);
  float t = __expf(z);
  return x - x / (t + 1.f);
}

// ================= device bodies =================

__device__ __forceinline__ void prep_body(
    int bid, const float* __restrict__ emb, bf16* __restrict__ ebf,
    const float* __restrict__ lin_w, const float* __restrict__ qw,
    const float* __restrict__ aw, bf16* __restrict__ WT,
    const float* __restrict__ kw, const float* __restrict__ kb,
    const float* __restrict__ vw, const float* __restrict__ vb,
    const float* __restrict__ a_rel, const float* __restrict__ m_rel,
    bf16* __restrict__ WRT, float* __restrict__ Bf)
{
  if (bid < 3125) {
    long i = ((long)bid * 256 + threadIdx.x) * 8;
    float4 f0 = *(const float4*)(emb + i);
    float4 f1 = *(const float4*)(emb + i + 4);
    short8 o;
    o[0]=f2bs(f0.x); o[1]=f2bs(f0.y); o[2]=f2bs(f0.z); o[3]=f2bs(f0.w);
    o[4]=f2bs(f1.x); o[5]=f2bs(f1.y); o[6]=f2bs(f1.z); o[7]=f2bs(f1.w);
    *(short8*)(ebf + i) = o;
  } else if (bid < 3765) {
    int lb = bid - 3125;
    int mat = lb >> 6;
    const float* src = (mat < 2) ? lin_w + mat * 16384
                     : (mat < 6) ? qw + (mat - 2) * 16384
                                 : aw + (mat - 6) * 16384;
    bf16* dst = WT + mat * 16384;
    int idx = (lb & 63) * 256 + threadIdx.x;     // n*128+k
    int n = idx >> 7, k = idx & 127;
    dst[idx] = __float2bfloat16(src[k * 128 + n]);
  } else {
    int lb = bid - 3765;
    int y = lb >> 6;
    bool isV = y >= 6;
    int z = isV ? y - 6 : y;
    int l = z / 3, r = z % 3, st = (r == 2) ? 1 : 0;
    const float* W   = (isV ? vw : kw) + (l * 2 + st) * 16384;
    const float* b   = (isV ? vb : kb) + (l * 2 + st) * 128;
    const float* rel = (isV ? m_rel : a_rel) + z * 2048;
    bf16* Wrt = WRT + y * 16384;
    float* br = Bf + y * 128;

    int idx = (lb & 63) * 256 + threadIdx.x;
    if (idx < 128 * 128) {
      int c = idx >> 7, o = idx & 127;
      int h = o >> 4, e = o & 15;
      float acc = 0.f;
#pragma unroll
      for (int d = 0; d < 16; d++)
        acc += W[c * 128 + h * 16 + d] * rel[h * 256 + d * 16 + e];
      Wrt[o * 128 + c] = __float2bfloat16(acc);
    }
    if (idx < 128) {
      int h = idx >> 4, e = idx & 15;
      float acc = 0.f;
#pragma unroll
      for (int d = 0; d < 16; d++)
        acc += b[h * 16 + d] * rel[h * 256 + d * 16 + e];
      br[idx] = acc;
    }
  }
}

__device__ __forceinline__ void pool_body(
    int bid, const int* __restrict__ tok_s, const int* __restrict__ tok_f,
    const bf16* __restrict__ ebf, bf16* __restrict__ E_out)
{
  int n = bid * 4 + (threadIdx.x >> 6);
  int lane = threadIdx.x & 63, g = lane >> 4, c16 = lane & 15;
  const int* tok = (n < N_STMT) ? (tok_s + n * 16) : (tok_f + (n - N_STMT) * 16);
  float acc[8] = {0.f,0.f,0.f,0.f,0.f,0.f,0.f,0.f};
#pragma unroll
  for (int j = 0; j < 4; j++) {
    int v = tok[g * 4 + j];
    short8 row = *(const short8*)(ebf + (long)v * CCH + c16 * 8);
#pragma unroll
    for (int q = 0; q < 8; q++) acc[q] += bs2f(row[q]);
  }
#pragma unroll
  for (int q = 0; q < 8; q++) {
    acc[q] += __shfl_xor(acc[q], 16);
    acc[q] += __shfl_xor(acc[q], 32);
  }
  if (g == 0) {
    short8 o;
#pragma unroll
    for (int q = 0; q < 8; q++) o[q] = f2bs(fmaxf(acc[q] * (1.f/16.f), 0.f));
    *(short8*)(E_out + (long)n * CCH + c16 * 8) = o;
  }
}

// 2-type GEMM body, register-resident weights, pipelined A.
template <bool RELU, bool BLEND, bool OUT_BF16>
__device__ __forceinline__ void gemm_2t_body(
    int bid, const bf16* __restrict__ Ab, const bf16* __restrict__ Wt0,
    const bf16* __restrict__ Wt1, const float* __restrict__ bias0,
    const float* __restrict__ bias1, const bf16* __restrict__ oldx,
    void* __restrict__ dstv, const float* __restrict__ skip2)
{
  const int wave = threadIdx.x >> 6, lane = threadIdx.x & 63;
  const int lane15 = lane & 15, quad = lane >> 4;
  const int jc0 = wave * 2;
  const int type = (bid >= GS2);
  const long base = type ? (long)N_STMT * CCH : 0;
  const int Nrows = type ? N_FUNC : N_STMT;
  long row = (long)(type ? bid - GS2 : bid) * RPB2;
  long rowEnd = row + RPB2; if (rowEnd > Nrows) rowEnd = Nrows;
  const bf16* Wt = type ? Wt1 : Wt0;
  const float* bias = type ? bias1 : bias0;

  short8 w[2][4];
#pragma unroll
  for (int jj = 0; jj < 2; jj++)
#pragma unroll
    for (int kq = 0; kq < 4; kq++)
      w[jj][kq] = *(const short8*)(
          Wt + ((jc0 + jj) * 16 + lane15) * CCH + kq * 32 + quad * 8);
  float4 bb[2];
#pragma unroll
  for (int jj = 0; jj < 2; jj++)
    bb[jj] = *(const float4*)(bias + (jc0 + jj) * 16 + quad * 4);

  float g = 1.f, gi = 0.f;
  if (BLEND) {
    float sk = skip2[type];
    g = 1.f / (1.f + expf(-sk));
    gi = 1.f - g;
  }

  // prime first A tile
  short8 a[4];
  {
    long r = row + lane15; if (r >= Nrows) r = Nrows - 1;
#pragma unroll
    for (int kq = 0; kq < 4; kq++)
      a[kq] = *(const short8*)(Ab + base + r * CCH + kq * 32 + quad * 8);
  }

  for (; row < rowEnd; row += 16) {
    short8 an[4];
    {
      long nrow = (row + 16 < rowEnd) ? row + 16 : row;
      long r = nrow + lane15; if (r >= Nrows) r = Nrows - 1;
#pragma unroll
      for (int kq = 0; kq < 4; kq++)
        an[kq] = *(const short8*)(Ab + base + r * CCH + kq * 32 + quad * 8);
    }

    floatx4 acc[2];
#pragma unroll
    for (int jj = 0; jj < 2; jj++) {
      acc[jj][0] = bb[jj].x; acc[jj][1] = bb[jj].y;
      acc[jj][2] = bb[jj].z; acc[jj][3] = bb[jj].w;
    }
#pragma unroll
    for (int kq = 0; kq < 4; kq++)
#pragma unroll
      for (int jj = 0; jj < 2; jj++)
        acc[jj] = __builtin_amdgcn_mfma_f32_16x16x32_bf16(
            w[jj][kq], a[kq], acc[jj], 0, 0, 0);

    long r = row + lane15;
    if (r < Nrows) {
#pragma unroll
      for (int jj = 0; jj < 2; jj++) {
        int c0 = (jc0 + jj) * 16 + quad * 4;
        long idx = base + r * CCH + c0;
        float v[4];
#pragma unroll
        for (int q = 0; q < 4; q++) v[q] = acc[jj][q];
        if (RELU) {
#pragma unroll
          for (int q = 0; q < 4; q++) v[q] = fmaxf(v[q], 0.f);
        }
        if (BLEND) {
          s4v ov = *(const s4v*)(oldx + idx);
#pragma unroll
          for (int q = 0; q < 4; q++) v[q] = g * v[q] + gi * bs2f(ov[q]);
        }
        if (OUT_BF16) {
          s4v o;
#pragma unroll
          for (int q = 0; q < 4; q++) o[q] = f2bs(v[q]);
          *(s4v*)((bf16*)dstv + idx) = o;
        } else {
          float4 o = make_float4(v[0], v[1], v[2], v[3]);
          *(float4*)((float*)dstv + idx) = o;
        }
      }
    }
#pragma unroll
    for (int kq = 0; kq < 4; kq++) a[kq] = an[kq];
  }
}

// ================= fused front dispatches =================

// front1: csr_count (3*EB blocks, FIRST to overlap) || prep (PREPB blocks)
__global__ __launch_bounds__(256) void front1(
    const float* __restrict__ emb, bf16* __restrict__ ebf,
    const float* __restrict__ lin_w, const float* __restrict__ qw,
    const float* __restrict__ aw, bf16* __restrict__ WT,
    const float* __restrict__ kw, const float* __restrict__ kb,
    const float* __restrict__ vw, const float* __restrict__ vb,
    const float* __restrict__ a_rel, const float* __restrict__ m_rel,
    bf16* __restrict__ WRT, float* __restrict__ Bf,
    const int* __restrict__ d0, const int* __restrict__ d1,
    const int* __restrict__ d2, int* __restrict__ degf,
    int* __restrict__ posf)
{
  int bid = blockIdx.x;
  if (bid < 3 * EB) {
    int r = bid / EB;
    int e = (bid % EB) * 256 + threadIdx.x;
    if (e < EDGES) {
      const int* dst = r == 0 ? d0 : r == 1 ? d1 : d2;
      int off = r == 0 ? 0 : r == 1 ? 100000 : 150000;
      posf[r * EDGES + e] = atomicAdd(&degf[off + dst[e]], 1);
    }
  } else {
    prep_body(bid - 3 * EB, emb, ebf, lin_w, qw, aw, WT, kw, kb, vw, vb,
              a_rel, m_rel, WRT, Bf);
  }
}

// front2: csr_alloc (ALLOCB blocks FIRST; block-scan -> ONE atomic/block)
//         || pool (POOLB blocks)
__global__ __launch_bounds__(256) void front2(
    const int* __restrict__ tok_s, const int* __restrict__ tok_f,
    const bf16* __restrict__ ebf, bf16* __restrict__ E_out,
    const int* __restrict__ degf, int* __restrict__ rowstartf,
    int* __restrict__ total)
{
  __shared__ int ws[4];
  int bid = blockIdx.x;
  if (bid < ALLOCB) {
    int r, base, Nd, b2;
    if (bid < 391)      { r = 0; base = 0;      Nd = 100000; b2 = bid; }
    else if (bid < 587) { r = 1; base = 100000; Nd = 50000;  b2 = bid - 391; }
    else                { r = 2; base = 150000; Nd = 100000; b2 = bid - 587; }
    int n = b2 * 256 + threadIdx.x;
    int d = (n < Nd) ? degf[base + n] : 0;
    int lane = threadIdx.x & 63, wv = threadIdx.x >> 6;
    // intra-wave inclusive scan
    int scan = d;
#pragma unroll
    for (int off = 1; off < 64; off <<= 1) {
      int t = __shfl_up(scan, off);
      if (lane >= off) scan += t;
    }
    if (lane == 63) ws[wv] = scan;       // wave totals
    __syncthreads();
    if (threadIdx.x == 0) {
      int s0 = ws[0], s1 = ws[1], s2 = ws[2], s3 = ws[3];
      int bb = atomicAdd(total + r, s0 + s1 + s2 + s3);   // ONE atomic/block
      ws[0] = bb; ws[1] = bb + s0; ws[2] = bb + s0 + s1;
      ws[3] = bb + s0 + s1 + s2;
    }
    __syncthreads();
    if (n < Nd) rowstartf[base + n] = ws[wv] + scan - d;  // exclusive prefix
  } else {
    pool_body(bid - ALLOCB, tok_s, tok_f, ebf, E_out);
  }
}

// front3: csr_fill (3*EB blocks FIRST) || prologue linear (GS2+GF2 blocks)
__global__ __launch_bounds__(256) void front3(
    const bf16* __restrict__ Ab, const bf16* __restrict__ Wt0,
    const bf16* __restrict__ Wt1, const float* __restrict__ bias0,
    const float* __restrict__ bias1, bf16* __restrict__ Xb,
    const int* __restrict__ d0, const int* __restrict__ d1,
    const int* __restrict__ d2, const int* __restrict__ s0,
    const int* __restrict__ s1, const int* __restrict__ s2,
    const int* __restrict__ rowstartf, const int* __restrict__ posf,
    int* __restrict__ srcs0, int* __restrict__ srcs1, int* __restrict__ srcs2)
{
  int bid = blockIdx.x;
  if (bid < 3 * EB) {
    int r = bid / EB;
    int e = (bid % EB) * 256 + threadIdx.x;
    if (e < EDGES) {
      const int* dst = r == 0 ? d0 : r == 1 ? d1 : d2;
      const int* src = r == 0 ? s0 : r == 1 ? s1 : s2;
      int* sr = r == 0 ? srcs0 : r == 1 ? srcs1 : srcs2;
      int off = r == 0 ? 0 : r == 1 ? 100000 : 150000;
      sr[rowstartf[off + dst[e]] + posf[r * EDGES + e]] = src[e];
    }
  } else {
    gemm_2t_body<true, false, true>(bid - 3 * EB, Ab, Wt0, Wt1, bias0, bias1,
                                    nullptr, Xb, nullptr);
  }
}

// ================= main-loop kernels =================

// out-proj + gated skip blend (standalone)
template <bool RELU, bool BLEND, bool OUT_BF16>
__global__ __launch_bounds__(256) void gemm_2t_reg(
    const bf16* __restrict__ Ab, const bf16* __restrict__ Wt0,
    const bf16* __restrict__ Wt1, const float* __restrict__ bias0,
    const float* __restrict__ bias1, const bf16* __restrict__ oldx,
    void* __restrict__ dstv, const float* __restrict__ skip2)
{
  gemm_2t_body<RELU, BLEND, OUT_BF16>(blockIdx.x, Ab, Wt0, Wt1, bias0, bias1,
                                      oldx, dstv, skip2);
}

// QKV body, register-resident weights, jc-split waves
template <int NM, bool HASQ>
__device__ __forceinline__ void qkv_body(
    const bf16* __restrict__ Ab,
    const bf16* __restrict__ W0, const float* __restrict__ B0,
    const bf16* __restrict__ W1, const float* __restrict__ B1,
    const bf16* __restrict__ W2, const float* __restrict__ B2,
    bf16* __restrict__ Q, bf16* __restrict__ KV, int N, int rpb, int bid)
{
  const int wave = threadIdx.x >> 6, lane = threadIdx.x & 63;
  const int lane15 = lane & 15, quad = lane >> 4;
  const int jc0 = wave * 2;
  constexpr int KIDX = HASQ ? 1 : 0;
  constexpr int VIDX = KIDX + 1;

  long row = (long)bid * rpb;
  if (row >= N) return;
  long rowEnd = row + rpb; if (rowEnd > N) rowEnd = N;

  const bf16* Wm[3]  = {W0, W1, W2};
  const float* Bm[3] = {B0, B1, B2};

  short8 w[NM][2][4];
#pragma unroll
  for (int m = 0; m < NM; m++)
#pragma unroll
    for (int jj = 0; jj < 2; jj++)
#pragma unroll
      for (int kq = 0; kq < 4; kq++)
        w[m][jj][kq] = *(const short8*)(
            Wm[m] + ((jc0 + jj) * 16 + lane15) * CCH + kq * 32 + quad * 8);

  for (; row < rowEnd; row += 16) {
    long r = row + lane15;
    long rc = (r < N) ? r : (N - 1);
    short8 a[4];
#pragma unroll
    for (int kq = 0; kq < 4; kq++)
      a[kq] = *(const short8*)(Ab + rc * CCH + kq * 32 + quad * 8);

    floatx4 acc[NM][2];
#pragma unroll
    for (int m = 0; m < NM; m++)
#pragma unroll
      for (int jj = 0; jj < 2; jj++) {
        float4 bb = *(const float4*)(Bm[m] + (jc0 + jj) * 16 + quad * 4);
        acc[m][jj][0] = bb.x; acc[m][jj][1] = bb.y;
        acc[m][jj][2] = bb.z; acc[m][jj][3] = bb.w;
      }

#pragma unroll
    for (int kq = 0; kq < 4; kq++)
#pragma unroll
      for (int m = 0; m < NM; m++)
#pragma unroll
        for (int jj = 0; jj < 2; jj++)
          acc[m][jj] = __builtin_amdgcn_mfma_f32_16x16x32_bf16(
              w[m][jj][kq], a[kq], acc[m][jj], 0, 0, 0);

    if (r < N) {
#pragma unroll
      for (int jj = 0; jj < 2; jj++) {
        int c0 = (jc0 + jj) * 16 + quad * 4;
        if constexpr (HASQ) {
          s4v qo;
          qo[0] = f2bs(acc[0][jj][0]);
          qo[1] = f2bs(acc[0][jj][1]);
          qo[2] = f2bs(acc[0][jj][2]);
          qo[3] = f2bs(acc[0][jj][3]);
          *(s4v*)(Q + r * CCH + c0) = qo;
        }
        short8 kv;
        kv[0] = f2bs(acc[KIDX][jj][0]);
        kv[1] = f2bs(acc[KIDX][jj][1]);
        kv[2] = f2bs(acc[VIDX][jj][0]);
        kv[3] = f2bs(acc[VIDX][jj][1]);
        kv[4] = f2bs(acc[KIDX][jj][2]);
        kv[5] = f2bs(acc[KIDX][jj][3]);
        kv[6] = f2bs(acc[VIDX][jj][2]);
        kv[7] = f2bs(acc[VIDX][jj][3]);
        *(short8*)(KV + r * 256 + 2 * c0) = kv;
      }
    }
  }
}

// all three QKV GEMMs of one layer in a single dispatch
__global__ __launch_bounds__(256, 3) void qkv_all(
    const bf16* __restrict__ Xb, const bf16* __restrict__ WT,
    const bf16* __restrict__ WRT, const float* __restrict__ Bf,
    const float* __restrict__ qb,
    bf16* __restrict__ Qb, bf16* __restrict__ KV0,
    bf16* __restrict__ KV1, bf16* __restrict__ KV2, int l)
{
  const int bid = blockIdx.x;
  const int z0 = l * 3 + 0, z1 = l * 3 + 1, z2 = l * 3 + 2;
  if (bid < GA) {
    qkv_body<3, true>(Xb,
        WT + (2 + l * 2) * 16384, qb + (l * 2) * 128,
        WRT + z0 * 16384, Bf + z0 * 128,
        WRT + (6 + z0) * 16384, Bf + (6 + z0) * 128,
        Qb, KV0, N_STMT, 128, bid);
  } else if (bid < GA + GB) {
    qkv_body<2, false>(Xb,
        WRT + z1 * 16384, Bf + z1 * 128,
        WRT + (6 + z1) * 16384, Bf + (6 + z1) * 128,
        nullptr, nullptr,
        nullptr, KV1, N_STMT, 96, bid - GA);
  } else {
    qkv_body<3, true>(Xb + (long)N_STMT * CCH,
        WT + (2 + l * 2 + 1) * 16384, qb + (l * 2 + 1) * 128,
        WRT + z2 * 16384, Bf + z2 * 128,
        WRT + (6 + z2) * 16384, Bf + (6 + z2) * 128,
        Qb + (long)N_STMT * CCH, KV2, N_FUNC, 128, bid - GA - GB);
  }
}

// -------- per-relation message: 16-lane group, serial edges, no merges ------
__device__ __forceinline__ void relmsg_grp(
    int rs, int g, const int* __restrict__ srcs,
    const bf16* __restrict__ KV, float psc,
    const float* __restrict__ q, int lane, float* __restrict__ out)
{
  int p = lane & 15;
  int gbase = lane & 48;                 // first lane of this 16-lane group
  float den = 0.f;
  float a[8] = {0.f,0.f,0.f,0.f,0.f,0.f,0.f,0.f};
  for (int j0 = 0; j0 < g; j0 += 16) {
    int rem = g - j0; if (rem > 16) rem = 16;
    int sl = srcs[rs + j0 + (p < rem ? p : rem - 1)];
    for (int j = 0; j < rem; j++) {
      int s = __shfl(sl, gbase + j);
      const bf16* rowp = KV + (long)s * 256 + 16 * p;
      uint4 u0 = *(const uint4*)(rowp);
      uint4 u1 = *(const uint4*)(rowp + 8);
      float prod = q[0]*blo(u0.x) + q[1]*bhi(u0.x)
                 + q[2]*blo(u0.z) + q[3]*bhi(u0.z)
                 + q[4]*blo(u1.x) + q[5]*bhi(u1.x)
                 + q[6]*blo(u1.z) + q[7]*bhi(u1.z);
      prod += __shfl_xor(prod, 1);
      float ev = __expf(prod * psc);
      den += ev;
      a[0] += ev * blo(u0.y); a[1] += ev * bhi(u0.y);
      a[2] += ev * blo(u0.w); a[3] += ev * bhi(u0.w);
      a[4] += ev * blo(u1.y); a[5] += ev * bhi(u1.y);
      a[6] += ev * blo(u1.w); a[7] += ev * bhi(u1.w);
    }
  }
  float inv = 1.f / (den + 1e-16f);
#pragma unroll
  for (int i = 0; i < 8; i++) out[i] = a[i] * inv;
}

// -------- fused aggregation + GELU: 16 nodes per block (4 per wave) ---------
__global__ __launch_bounds__(256) void agg_all(
    const int* __restrict__ rs0, const int* __restrict__ dg0, const int* __restrict__ srcs0,
    const int* __restrict__ rs1, const int* __restrict__ dg1, const int* __restrict__ srcs1,
    const int* __restrict__ rs2, const int* __restrict__ dg2, const int* __restrict__ srcs2,
    const bf16* __restrict__ KV0, const bf16* __restrict__ KV1,
    const bf16* __restrict__ KV2, const float* __restrict__ pl,
    const bf16* __restrict__ Qb, bf16* __restrict__ AGGb)
{
  int n = blockIdx.x * 16 + (threadIdx.x >> 4);
  if (n >= N_TOT) return;
  int lane = threadIdx.x & 63;
  int p = lane & 15, h = p >> 1;
  uint4 qv = *(const uint4*)(Qb + (long)n * CCH + 8 * p);
  float q[8];
  q[0] = blo(qv.x); q[1] = bhi(qv.x); q[2] = blo(qv.y); q[3] = bhi(qv.y);
  q[4] = blo(qv.z); q[5] = bhi(qv.z); q[6] = blo(qv.w); q[7] = bhi(qv.w);
  float m[8];
  if (n < N_STMT) {
    float m0[8], m2[8];
    relmsg_grp(rs0[n], dg0[n], srcs0, KV0, pl[h] * 0.25f, q, lane, m0);
    relmsg_grp(rs2[n], dg2[n], srcs2, KV2, pl[16 + h] * 0.25f, q, lane, m2);
#pragma unroll
    for (int i = 0; i < 8; i++) m[i] = m0[i] + m2[i];
  } else {
    int nf = n - N_STMT;
    relmsg_grp(rs1[nf], dg1[nf], srcs1, KV1, pl[8 + h] * 0.25f, q, lane, m);
  }
  short8 o;
#pragma unroll
  for (int i = 0; i < 8; i++) o[i] = f2bs(gelu_f(m[i]));
  *(short8*)(AGGb + (long)n * CCH + 8 * p) = o;
}

__global__ __launch_bounds__(256) void zero_out_k(float* __restrict__ out)
{
  long i = ((long)blockIdx.x * 256 + threadIdx.x) * 4;
  *(float4*)(out + i) = make_float4(0.f, 0.f, 0.f, 0.f);
}

extern "C" void kernel_launch(void* const* d_in, const int* in_sizes, int n_in,
                              void* d_out, int out_size, void* d_ws, size_t ws_size,
                              hipStream_t stream)
{
  const int* tok_s = (const int*)d_in[0];
  const int* tok_f = (const int*)d_in[1];
  const int* esrc[3] = {(const int*)d_in[2], (const int*)d_in[4], (const int*)d_in[6]};
  const int* edst[3] = {(const int*)d_in[3], (const int*)d_in[5], (const int*)d_in[7]};
  const float* emb   = (const float*)d_in[8];
  const float* lin_w = (const float*)d_in[9];
  const float* lin_b = (const float*)d_in[10];
  const float* kw = (const float*)d_in[11];
  const float* kb = (const float*)d_in[12];
  const float* qw = (const float*)d_in[13];
  const float* qb = (const float*)d_in[14];
  const float* vw = (const float*)d_in[15];
  const float* vb = (const float*)d_in[16];
  const float* aw = (const float*)d_in[17];
  const float* ab = (const float*)d_in[18];
  const float* skip  = (const float*)d_in[19];
  const float* a_rel = (const float*)d_in[20];
  const float* m_rel = (const float*)d_in[21];
  const float* p_rel = (const float*)d_in[22];

  // ---- ws layout. ----
  float* Bf   = (float*)d_ws;           // 12 x 128 fused biases
  bf16*  Xb   = (bf16*)(Bf + 1536);     // 19,200,000  residual stream
  bf16*  AGGb = Xb  + 19200000L;        // 19,200,000  agg out (alias pooled E)
  bf16*  KV0  = AGGb + 19200000L;       // 25,600,000  stmt r0 KV interleaved
  bf16*  KV1  = KV0 + 25600000L;        // 25,600,000  stmt r1 KV
  bf16*  KV2  = KV1 + 25600000L;        // 12,800,000  func r2 KV
  bf16*  WT   = KV2 + 12800000L;        //    163,840  10 transposed raw mats
  bf16*  WRT  = WT  + 163840L;          //    196,608  12 fused rel mats
  int*   ip   = (int*)(WRT + 196608L);
  int* degf        = ip;                               // 250,000 contiguous
  int* total       = ip + 250000;                      // 4 counters (3 used)
  int* rowstartf   = ip + 250004;                      // 250,000 contiguous
  int* rowstart[3] = {ip + 250004, ip + 350004, ip + 400004};
  int* deg[3]      = {ip, ip + 100000, ip + 150000};
  int* srcs[3]     = {ip + 500004, ip + 700004, ip + 900004};
  int* posf        = ip + 1100004;                     // 3 x 200,000
  bf16* EBF   = KV0;                    // 6,400,000 alias: bf16 emb table,
                                        // dead before KV0 is first written
  bf16*  Qb   = (bf16*)d_out;          // bf16 Q scratch in fp32 d_out,
  float* OUTF = (float*)d_out;         // consumed before epilogue overwrites

  const size_t NEED = (size_t)1536 * 4 + (size_t)102760448 * 2
                    + (size_t)1700004 * 4;
  if (ws_size < NEED) {            // soft-fail diagnostic: absmax == |ref|max
    zero_out_k<<<19200000 / 4 / 256, 256, 0, stream>>>(OUTF);
    return;
  }

  // ---- fused front: (count || prep) -> (alloc || pool) -> (fill || lin) ----
  hipMemsetAsync(ip, 0, (size_t)250004 * 4, stream);
  front1<<<3 * EB + PREPB, 256, 0, stream>>>(
      emb, EBF, lin_w, qw, aw, WT, kw, kb, vw, vb, a_rel, m_rel, WRT, Bf,
      edst[0], edst[1], edst[2], degf, posf);
  front2<<<ALLOCB + POOLB, 256, 0, stream>>>(
      tok_s, tok_f, EBF, AGGb, degf, rowstartf, total);
  front3<<<3 * EB + GS2 + GF2, 256, 0, stream>>>(
      AGGb, WT, WT + 16384, lin_b, lin_b + 128, Xb,
      edst[0], edst[1], edst[2], esrc[0], esrc[1], esrc[2],
      rowstartf, posf, srcs[0], srcs[1], srcs[2]);

  for (int l = 0; l < 2; l++) {
    // all three QKV GEMMs in one dispatch
    qkv_all<<<GA + GB + GF, 256, 0, stream>>>(
        Xb, WT, WRT, Bf, qb, Qb, KV0, KV1, KV2, l);
    // fused aggregation (+GELU) over all nodes, 16 nodes/block
    agg_all<<<(N_TOT + 15) / 16, 256, 0, stream>>>(
        rowstart[0], deg[0], srcs[0], rowstart[1], deg[1], srcs[1],
        rowstart[2], deg[2], srcs[2], KV0, KV1, KV2,
        p_rel + l * 24, Qb, AGGb);
    // fused out-proj + gated skip blend. l=0 -> Xb; l=1 -> fp32 d_out.
    if (l == 0)
      gemm_2t_reg<false, true, true><<<GS2 + GF2, 256, 0, stream>>>(
          AGGb, WT + 6 * 16384, WT + 7 * 16384, ab, ab + 128,
          Xb, Xb, skip);
    else
      gemm_2t_reg<false, true, false><<<GS2 + GF2, 256, 0, stream>>>(
          AGGb, WT + 8 * 16384, WT + 9 * 16384, ab + 256, ab + 384,
          Xb, OUTF, skip + 2);
  }
}